// Round 16
// baseline (1626.572 us; speedup 1.0000x reference)
//
#include <hip/hip_runtime.h>
#include <hip/hip_bf16.h>
#include <math.h>

#define BT 32768        // B*T tokens
#define HH 1024

typedef unsigned short u16;
typedef unsigned int u32;
typedef __attribute__((ext_vector_type(4))) unsigned short u16x4;
typedef __attribute__((ext_vector_type(8))) unsigned short u16x8;
typedef __attribute__((ext_vector_type(8))) __bf16 bf16x8;
typedef __attribute__((ext_vector_type(4))) float f32x4;

#define DEVI static __device__ __forceinline__

DEVI u16 f2bf(float f){
  unsigned u = __builtin_bit_cast(unsigned, f);
  u += 0x7FFFu + ((u >> 16) & 1u);
  return (u16)(u >> 16);
}
DEVI float bf2f(u16 h){
  unsigned u = ((unsigned)h) << 16;
  return __builtin_bit_cast(float, u);
}
DEVI void gl_lds16(const void* g, void* l){
  __builtin_amdgcn_global_load_lds((const __attribute__((address_space(1))) void*)g,
                                   (__attribute__((address_space(3))) void*)l, 16, 0, 0);
}
// T2 swizzle: 16B-granule XOR within a 64-elem (128B) row. elem units of u16. Involution.
DEVI int swz(int row, int elem){ return elem ^ ((row & 7) << 3); }

// ---------------- elementwise prep kernels ----------------
__global__ void k_cast4(const float* __restrict__ s, u16* __restrict__ d, int n4){
  int i = blockIdx.x*blockDim.x + threadIdx.x;
  int st = gridDim.x*blockDim.x;
  for (; i < n4; i += st){
    float4 v = ((const float4*)s)[i];
    u16x4 o = { f2bf(v.x), f2bf(v.y), f2bf(v.z), f2bf(v.w) };
    ((u16x4*)d)[i] = o;
  }
}

// qb = bf16(query_token + static_context)
__global__ void k_qb(const float* __restrict__ qt, const float* __restrict__ sc,
                     u16* __restrict__ d, int n4){
  int i = blockIdx.x*blockDim.x + threadIdx.x;
  int st = gridDim.x*blockDim.x;
  for (; i < n4; i += st){
    int e = i*4; int c = e & 1023;
    float4 v = *(const float4*)&sc[e];
    float4 q = *(const float4*)&qt[c];
    u16x4 o = { f2bf(v.x+q.x), f2bf(v.y+q.y), f2bf(v.z+q.z), f2bf(v.w+q.w) };
    ((u16x4*)d)[i] = o;
  }
}

__global__ void k_copyf(const float* __restrict__ s, float* __restrict__ d, int n){
  int i = blockIdx.x*blockDim.x + threadIdx.x;
  int st = gridDim.x*blockDim.x;
  for (; i < n; i += st) d[i] = s[i];
}

// weights = mean over 16 heads of pbuf[t][h][m]
__global__ void k_wmean(const float* __restrict__ p, float* __restrict__ out, int n){
  int i = blockIdx.x*blockDim.x + threadIdx.x;
  int st = gridDim.x*blockDim.x;
  for (; i < n; i += st){
    int t = i/3, m = i - t*3;
    float s = 0.f;
    #pragma unroll
    for (int h = 0; h < 16; ++h) s += p[(size_t)t*48 + h*3 + m];
    out[i] = s * 0.0625f;
  }
}

// transpose-cast: s[R][C] f32 -> d[C][R] bf16
__global__ void k_transcast(const float* __restrict__ s, u16* __restrict__ d, int R, int C){
  __shared__ float tile[32][33];
  int c0 = blockIdx.x*32, r0 = blockIdx.y*32;
  int tx = threadIdx.x & 31, ty = threadIdx.x >> 5;   // 32 x 8
  #pragma unroll
  for (int i = 0; i < 32; i += 8) tile[ty+i][tx] = s[(size_t)(r0+ty+i)*C + c0+tx];
  __syncthreads();
  #pragma unroll
  for (int i = 0; i < 32; i += 8) d[(size_t)(c0+ty+i)*R + r0+tx] = f2bf(tile[tx][ty+i]);
}

// out[row] = dot(W[row,:](bf16), x(f32)) + badd[row], rows = gridDim.x*4
__global__ void k_matvec(const u16* __restrict__ W, const float* __restrict__ x,
                         const float* __restrict__ badd, float* __restrict__ out, int K){
  int row = blockIdx.x*4 + (threadIdx.x>>6);
  int lane = threadIdx.x & 63;
  float s = 0.f;
  for (int k = lane; k < K; k += 64) s += bf2f(W[(size_t)row*K + k]) * x[k];
  #pragma unroll
  for (int m = 1; m < 64; m <<= 1) s += __shfl_xor(s, m);
  if (lane == 0) out[row] = s + badd[row];
}

// ---------------- GEMM 128x128 (R2-proven) ----------------
__global__ __launch_bounds__(256, 3)
void k_gemm(const u16* __restrict__ A, int lda,
            const u16* __restrict__ B, int ldb, int K,
            const float* __restrict__ bias,
            u16* __restrict__ C, int ldc, int col0, int act)
{
  __shared__ u16 As[128*64];
  __shared__ u16 Bs[128*64];
  const int tid = threadIdx.x, lane = tid & 63, wid = tid >> 6;
  const int wr = wid >> 1, wc = wid & 1;
  const int r15 = lane & 15, g = lane >> 4;
  const int m0 = blockIdx.x * 128, n0 = blockIdx.y * 128;
  f32x4 acc[4][4] = {};

  for (int k0 = 0; k0 < K; k0 += 64){
    #pragma unroll
    for (int it = 0; it < 4; ++it){
      int c = it*256 + tid;
      int row = c >> 3;
      int ke = swz(row, (c & 7) * 8);
      gl_lds16(A + (size_t)(m0+row)*lda + (k0+ke), As + c*8);
      gl_lds16(B + (size_t)(n0+row)*ldb + (k0+ke), Bs + c*8);
    }
    __syncthreads();
    #pragma unroll
    for (int kk = 0; kk < 64; kk += 32){
      bf16x8 av[4], bvv[4];
      #pragma unroll
      for (int i = 0; i < 4; ++i){
        int row = wr*64 + i*16 + r15;
        av[i] = *(const bf16x8*)&As[row*64 + swz(row, kk + g*8)];
      }
      #pragma unroll
      for (int j = 0; j < 4; ++j){
        int row = wc*64 + j*16 + r15;
        bvv[j] = *(const bf16x8*)&Bs[row*64 + swz(row, kk + g*8)];
      }
      #pragma unroll
      for (int i = 0; i < 4; ++i)
        #pragma unroll
        for (int j = 0; j < 4; ++j)
          acc[i][j] = __builtin_amdgcn_mfma_f32_16x16x32_bf16(av[i], bvv[j], acc[i][j], 0, 0, 0);
    }
    __syncthreads();
  }
  #pragma unroll
  for (int j = 0; j < 4; ++j){
    int col = wc*64 + j*16 + r15;
    float bb = bias ? bias[n0 + col] : 0.f;
    #pragma unroll
    for (int i = 0; i < 4; ++i){
      #pragma unroll
      for (int jj = 0; jj < 4; ++jj){
        int row = wr*64 + i*16 + g*4 + jj;
        float v = acc[i][j][jj] + bb;
        if (act == 1) v = 0.5f * v * (1.f + erff(v * 0.70710678118654752f));
        C[(size_t)(m0+row)*ldc + col0 + n0 + col] = f2bf(v);
      }
    }
  }
}

// ---------------- fused attention: K-GEMM -> scores -> softmax -> V-GEMM -> ctx -------
// Block = 128 tokens x 128 cols (2 heads), 256 thr, 4 waves at 64x64 (k_gemm density).
// Single-accumulator design to reach 3 blocks/CU (R15 had acc+cx = 128 VGPR -> 2 blocks):
//  - pass 1: Q is NOT register-hoisted; after each modality's GEMM the (dead) As/Bs
//    tiles are re-staged with the Q tile (head0 cols -> As, head1 -> Bs) and scores
//    read Q from LDS.
//  - pass 2: flash-style rescale -- acc_m = (sum_{m'<=m} p_m' G_m')/p_m via
//    acc *= p_{m-1}/p_m between modalities; final cx = acc*p_2 + sum_m p_m bv_m.
// Softmax block-local; per-head probs to pbuf for k_wmean. XCD-contiguous bid remap.
__global__ __launch_bounds__(256, 3)
void k_attnf(const u16* __restrict__ x0b, const u16* __restrict__ x1b, const u16* __restrict__ x2b,
             const u16* __restrict__ Wc0, const u16* __restrict__ Wc1, const u16* __restrict__ Wc2,
             const float* __restrict__ bc0, const float* __restrict__ bc1, const float* __restrict__ bc2,
             const u16* __restrict__ Qg, u16* __restrict__ ctx, float* __restrict__ pbuf)
{
  __shared__ u16 As[128*64];
  __shared__ u16 Bs[128*64];
  __shared__ float Sl[2*128*3];    // scores -> probs (in place)
  const int tid = threadIdx.x, lane = tid & 63, wid = tid >> 6;
  const int wr = wid >> 1, wc = wid & 1;
  const int r15 = lane & 15, g = lane >> 4;
  const int bid = blockIdx.x;
  const int xcd = bid & 7, bn = (bid >> 3) & 7, btb = (bid >> 6) * 8 + xcd;
  const int t0 = btb * 128, n0 = bn * 128;

  const u16* Xs[3] = { x0b, x1b, x2b };
  const u16* Ws[3] = { Wc0, Wc1, Wc2 };
  const float* Bc[3] = { bc0, bc1, bc2 };
  const int Ks[3] = { 256, 512, 1024 };

  // ---------------- pass 1: K-GEMM panels + LDS-Q score epilogues ----------------
  #pragma unroll
  for (int m = 0; m < 3; ++m){
    const int K = Ks[m];
    const u16* X = Xs[m];
    const u16* W = Ws[m];
    f32x4 acc[4][4] = {};
    for (int k0 = 0; k0 < K; k0 += 64){
      #pragma unroll
      for (int it = 0; it < 4; ++it){
        int c = it*256 + tid;
        int row = c >> 3;
        int ke = swz(row, (c & 7) * 8);
        gl_lds16(X + (size_t)(t0+row)*K + (k0+ke), As + c*8);
        gl_lds16(W + (size_t)(n0+row)*K + (k0+ke), Bs + c*8);
      }
      __syncthreads();
      #pragma unroll
      for (int kk = 0; kk < 64; kk += 32){
        bf16x8 av[4], bvv[4];
        #pragma unroll
        for (int i = 0; i < 4; ++i){
          int row = wr*64 + i*16 + r15;
          av[i] = *(const bf16x8*)&As[row*64 + swz(row, kk + g*8)];
        }
        #pragma unroll
        for (int j = 0; j < 4; ++j){
          int row = wc*64 + j*16 + r15;
          bvv[j] = *(const bf16x8*)&Bs[row*64 + swz(row, kk + g*8)];
        }
        #pragma unroll
        for (int i = 0; i < 4; ++i)
          #pragma unroll
          for (int j = 0; j < 4; ++j)
            acc[i][j] = __builtin_amdgcn_mfma_f32_16x16x32_bf16(av[i], bvv[j], acc[i][j], 0, 0, 0);
      }
      __syncthreads();
    }
    // stage Q tile into (dead) As/Bs: As = head0 cols 0-63, Bs = head1 cols 64-127
    #pragma unroll
    for (int it = 0; it < 4; ++it){
      int c = it*256 + tid;
      int row = c >> 3;
      int ke = swz(row, (c & 7) * 8);
      gl_lds16(Qg + (size_t)(t0+row)*1024 + n0 + ke,      As + c*8);
      gl_lds16(Qg + (size_t)(t0+row)*1024 + n0 + 64 + ke, Bs + c*8);
    }
    __syncthreads();
    // scores for modality m; this wave's head = bn*2 + wc, Q from LDS
    const u16* QL = wc ? Bs : As;
    float bkc[4];
    #pragma unroll
    for (int j = 0; j < 4; ++j) bkc[j] = Bc[m][n0 + wc*64 + j*16 + r15];
    #pragma unroll
    for (int i = 0; i < 4; ++i){
      #pragma unroll
      for (int jj = 0; jj < 4; ++jj){
        int row = wr*64 + i*16 + g*4 + jj;
        float sv = 0.f;
        #pragma unroll
        for (int j = 0; j < 4; ++j)
          sv += (acc[i][j][jj] + bkc[j]) * bf2f(QL[row*64 + swz(row, j*16 + r15)]);
        sv += __shfl_xor(sv, 1); sv += __shfl_xor(sv, 2);
        sv += __shfl_xor(sv, 4); sv += __shfl_xor(sv, 8);
        if (r15 == 0) Sl[(wc*128 + row)*3 + m] = sv * 0.125f;
      }
    }
    __syncthreads();   // Q-tile reads done before next modality overwrites As/Bs
  }

  // ---------------- softmax (block-local) + per-head prob store ----------------
  {
    int h2 = tid >> 7, tt = tid & 127;
    int base = (h2*128 + tt)*3;
    float s0 = Sl[base+0], s1 = Sl[base+1], s2 = Sl[base+2];
    float mx = fmaxf(s0, fmaxf(s1, s2));
    float e0 = __expf(s0-mx), e1 = __expf(s1-mx), e2 = __expf(s2-mx);
    float inv = 1.f/(e0+e1+e2);
    e0 = fmaxf(e0*inv, 1e-30f); e1 = fmaxf(e1*inv, 1e-30f); e2 = fmaxf(e2*inv, 1e-30f);
    __syncthreads();                      // all reads of raw scores done
    Sl[base+0] = e0; Sl[base+1] = e1; Sl[base+2] = e2;
    float* pp = pbuf + ((size_t)(t0+tt)*16 + (bn*2 + h2))*3;
    pp[0] = e0; pp[1] = e1; pp[2] = e2;
  }
  __syncthreads();

  // ---------------- pass 2: V-GEMM with inter-modality rescale (single acc) --------
  {
    f32x4 acc[4][4] = {};
    #pragma unroll
    for (int m = 0; m < 3; ++m){
      const int K = Ks[m];
      const u16* X = Xs[m];
      const u16* W = Ws[m] + (size_t)1024*K;   // V rows of composite weight
      if (m > 0){
        #pragma unroll
        for (int i = 0; i < 4; ++i){
          #pragma unroll
          for (int jj = 0; jj < 4; ++jj){
            int row = wr*64 + i*16 + g*4 + jj;
            float r = Sl[(wc*128+row)*3 + (m-1)] / Sl[(wc*128+row)*3 + m];
            #pragma unroll
            for (int j = 0; j < 4; ++j) acc[i][j][jj] *= r;
          }
        }
      }
      for (int k0 = 0; k0 < K; k0 += 64){
        #pragma unroll
        for (int it = 0; it < 4; ++it){
          int c = it*256 + tid;
          int row = c >> 3;
          int ke = swz(row, (c & 7) * 8);
          gl_lds16(X + (size_t)(t0+row)*K + (k0+ke), As + c*8);
          gl_lds16(W + (size_t)(n0+row)*K + (k0+ke), Bs + c*8);
        }
        __syncthreads();
        #pragma unroll
        for (int kk = 0; kk < 64; kk += 32){
          bf16x8 av[4], bvv[4];
          #pragma unroll
          for (int i = 0; i < 4; ++i){
            int row = wr*64 + i*16 + r15;
            av[i] = *(const bf16x8*)&As[row*64 + swz(row, kk + g*8)];
          }
          #pragma unroll
          for (int j = 0; j < 4; ++j){
            int row = wc*64 + j*16 + r15;
            bvv[j] = *(const bf16x8*)&Bs[row*64 + swz(row, kk + g*8)];
          }
          #pragma unroll
          for (int i = 0; i < 4; ++i)
            #pragma unroll
            for (int j = 0; j < 4; ++j)
              acc[i][j] = __builtin_amdgcn_mfma_f32_16x16x32_bf16(av[i], bvv[j], acc[i][j], 0, 0, 0);
        }
        __syncthreads();
      }
    }
    // final: ctx = acc*p2 + sum_m p_m bv_m
    float bvc[3][4];
    #pragma unroll
    for (int m = 0; m < 3; ++m)
      #pragma unroll
      for (int j = 0; j < 4; ++j)
        bvc[m][j] = Bc[m][1024 + n0 + wc*64 + j*16 + r15];
    #pragma unroll
    for (int i = 0; i < 4; ++i){
      #pragma unroll
      for (int jj = 0; jj < 4; ++jj){
        int row = wr*64 + i*16 + g*4 + jj;
        float p0 = Sl[(wc*128+row)*3 + 0];
        float p1 = Sl[(wc*128+row)*3 + 1];
        float p2 = Sl[(wc*128+row)*3 + 2];
        #pragma unroll
        for (int j = 0; j < 4; ++j){
          float v = acc[i][j][jj]*p2 + p0*bvc[0][j] + p1*bvc[1][j] + p2*bvc[2][j];
          ctx[(size_t)(t0+row)*1024 + n0 + wc*64 + j*16 + r15] = f2bf(v);
        }
      }
    }
  }
}

// ---------------- LayerNorm (H=1024), optional bf16 residual, bf16 or f32 out ----------------
__global__ __launch_bounds__(256)
void k_ln(const u16* __restrict__ X, const u16* __restrict__ R,
          const float* __restrict__ gam, const float* __restrict__ bet,
          u16* __restrict__ outb, float* __restrict__ outf)
{
  __shared__ float rs[4], rq[4];
  const int t = blockIdx.x, tid = threadIdx.x;
  const size_t base = (size_t)t*1024 + tid*4;
  u16x4 xv = *(const u16x4*)&X[base];
  float v[4];
  #pragma unroll
  for (int i = 0; i < 4; ++i) v[i] = bf2f(xv[i]);
  if (R){
    u16x4 rv = *(const u16x4*)&R[base];
    #pragma unroll
    for (int i = 0; i < 4; ++i) v[i] += bf2f(rv[i]);
  }
  float s = v[0]+v[1]+v[2]+v[3];
  float q = v[0]*v[0]+v[1]*v[1]+v[2]*v[2]+v[3]*v[3];
  #pragma unroll
  for (int m = 1; m < 64; m <<= 1){ s += __shfl_xor(s, m); q += __shfl_xor(q, m); }
  if ((tid & 63) == 0){ rs[tid>>6] = s; rq[tid>>6] = q; }
  __syncthreads();
  s = rs[0]+rs[1]+rs[2]+rs[3];
  q = rq[0]+rq[1]+rq[2]+rq[3];
  float mean = s * (1.f/1024.f);
  float var  = q * (1.f/1024.f) - mean*mean;
  float rstd = rsqrtf(var + 1e-5f);
  int c0 = tid*4;
  if (outb){
    u16x4 o;
    #pragma unroll
    for (int i = 0; i < 4; ++i) o[i] = f2bf((v[i]-mean)*rstd*gam[c0+i] + bet[c0+i]);
    *(u16x4*)&outb[base] = o;
  } else {
    float4 o;
    o.x = (v[0]-mean)*rstd*gam[c0+0] + bet[c0+0];
    o.y = (v[1]-mean)*rstd*gam[c0+1] + bet[c0+1];
    o.z = (v[2]-mean)*rstd*gam[c0+2] + bet[c0+2];
    o.w = (v[3]-mean)*rstd*gam[c0+3] + bet[c0+3];
    *(float4*)&outf[base] = o;
  }
}

// ---------------- host launcher ----------------
extern "C" void kernel_launch(void* const* d_in, const int* in_sizes, int n_in,
                              void* d_out, int out_size, void* d_ws, size_t ws_size,
                              hipStream_t stream)
{
  (void)in_sizes; (void)n_in; (void)out_size;
  const float* x0  = (const float*)d_in[0];
  const float* x1  = (const float*)d_in[1];
  const float* x2  = (const float*)d_in[2];
  const float* sc  = (const float*)d_in[3];
  const float* Wp0 = (const float*)d_in[4];  const float* bp0 = (const float*)d_in[5];
  const float* Wp1 = (const float*)d_in[6];  const float* bp1 = (const float*)d_in[7];
  const float* Wq  = (const float*)d_in[8];  const float* bq  = (const float*)d_in[9];
  const float* Wk  = (const float*)d_in[10]; const float* bk  = (const float*)d_in[11];
  const float* Wv  = (const float*)d_in[12]; const float* bv  = (const float*)d_in[13];
  const float* Wo  = (const float*)d_in[14]; const float* bo  = (const float*)d_in[15];
  const float* qt  = (const float*)d_in[16];
  const float* g1  = (const float*)d_in[17]; const float* be1 = (const float*)d_in[18];
  const float* g2  = (const float*)d_in[19]; const float* be2 = (const float*)d_in[20];
  const float* W1  = (const float*)d_in[21]; const float* b1  = (const float*)d_in[22];
  const float* W2  = (const float*)d_in[23]; const float* b2  = (const float*)d_in[24];

  char* ws = (char*)d_ws;
  size_t off = 0;
  auto alloc = [&](size_t b)->char*{ char* p = ws + off; off += (b + 255) & ~(size_t)255; return p; };

  u16* Wqb   = (u16*)alloc((size_t)1024*1024*2);
  u16* Wob   = (u16*)alloc((size_t)1024*1024*2);
  u16* W1b   = (u16*)alloc((size_t)4096*1024*2);
  u16* W2b   = (u16*)alloc((size_t)1024*4096*2);
  u16* Wkvb  = (u16*)alloc((size_t)2048*1024*2);  // [Wk; Wv]
  u16* Wp0t  = (u16*)alloc((size_t)256*1024*2);   // Wp0^T
  u16* Wp1t  = (u16*)alloc((size_t)512*1024*2);   // Wp1^T
  u16* Wkv0c = (u16*)alloc((size_t)2048*256*2);   // [Wk;Wv]@Wp0
  u16* Wkv1c = (u16*)alloc((size_t)2048*512*2);   // [Wk;Wv]@Wp1
  float* bc0 = (float*)alloc((size_t)2048*4);
  float* bc1 = (float*)alloc((size_t)2048*4);
  float* bc2 = (float*)alloc((size_t)2048*4);
  char* regX  = alloc((size_t)BT*(256+512+1024)*2);  // x0b|x1b|x2b -> aob -> ff2b
  char* regQ1 = alloc((size_t)BT*1024*2);            // qb -> ctxb -> f1b
  char* regQ2 = alloc((size_t)BT*1024*2);            // Qb -> ff1c
  float* pbuf = (float*)alloc((size_t)BT*48*4);      // per-head probs
  if (off > ws_size) return;

  u16* x0b = (u16*)regX;
  u16* x1b = (u16*)(regX + (size_t)BT*256*2);
  u16* x2b = (u16*)(regX + (size_t)BT*768*2);
  u16* aob  = (u16*)regX;
  u16* ff2b = (u16*)regX;
  u16* qb   = (u16*)regQ1;
  u16* ctxb = (u16*)regQ1;
  u16* f1b  = (u16*)regQ1;
  u16* Qb   = (u16*)regQ2;
  u16* ff1c = (u16*)regQ2;

  dim3 B256(256);
  auto cast4 = [&](const float* s, u16* d, int n, int grid){
    k_cast4<<<dim3(grid), B256, 0, stream>>>(s, d, n >> 2);
  };
  cast4(Wq, Wqb, 1024*1024, 1024);
  cast4(Wk, Wkvb, 1024*1024, 1024);
  cast4(Wv, Wkvb + (size_t)1024*1024, 1024*1024, 1024);
  cast4(Wo, Wob, 1024*1024, 1024);
  cast4(W1, W1b, 4096*1024, 1024);
  cast4(W2, W2b, 4096*1024, 1024);
  cast4(x0, x0b, BT*256, 1024);
  cast4(x1, x1b, BT*512, 1024);
  cast4(x2, x2b, BT*1024, 2048);
  k_transcast<<<dim3(8, 32),  B256, 0, stream>>>(Wp0, Wp0t, 1024, 256);
  k_transcast<<<dim3(16, 32), B256, 0, stream>>>(Wp1, Wp1t, 1024, 512);
  k_copyf<<<dim3(4), B256, 0, stream>>>(bk, bc2, 1024);
  k_copyf<<<dim3(4), B256, 0, stream>>>(bv, bc2 + 1024, 1024);
  k_matvec<<<dim3(512), B256, 0, stream>>>(Wkvb, bp0, bc2, bc0, 1024);
  k_matvec<<<dim3(512), B256, 0, stream>>>(Wkvb, bp1, bc2, bc1, 1024);
  k_qb<<<dim3(2048), B256, 0, stream>>>(qt, sc, qb, BT*256);

  // composite weights: Wkv @ Wp_m  (C[2048, IN_m])
  k_gemm<<<dim3(16, 2), B256, 0, stream>>>(Wkvb, 1024, Wp0t, 1024, 1024, nullptr, Wkv0c, 256, 0, 0);
  k_gemm<<<dim3(16, 4), B256, 0, stream>>>(Wkvb, 1024, Wp1t, 1024, 1024, nullptr, Wkv1c, 512, 0, 0);

  k_gemm<<<dim3(BT/128, 8), B256, 0, stream>>>(qb, 1024, Wqb, 1024, 1024, bq, Qb, 1024, 0, 0);
  k_attnf<<<dim3(BT/128*8), B256, 0, stream>>>(x0b, x1b, x2b, Wkv0c, Wkv1c, Wkvb,
                                               bc0, bc1, bc2, Qb, ctxb, pbuf);
  float* outf = (float*)d_out;
  k_wmean<<<dim3(384), B256, 0, stream>>>(pbuf, outf + (size_t)BT*1024, BT*3);
  k_gemm<<<dim3(BT/128, 8), B256, 0, stream>>>(ctxb, 1024, Wob, 1024, 1024, bo, aob, 1024, 0, 0);
  k_ln<<<dim3(BT), B256, 0, stream>>>(aob, nullptr, g1, be1, f1b, nullptr);

  for (int c = 0; c < 4; ++c){
    const u16* fa = f1b + (size_t)c*8192*1024;
    k_gemm<<<dim3(64, 32), B256, 0, stream>>>(fa, 1024, W1b, 1024, 1024, b1, ff1c, 4096, 0, 1);
    k_gemm<<<dim3(64, 8),  B256, 0, stream>>>(ff1c, 4096, W2b, 4096, 4096, b2,
                                              ff2b + (size_t)c*8192*1024, 1024, 0, 0);
  }
  k_ln<<<dim3(BT), B256, 0, stream>>>(ff2b, f1b, g2, be2, nullptr, outf);
}

// Round 17
// 1574.844 us; speedup vs baseline: 1.0328x; 1.0328x over previous
//
#include <hip/hip_runtime.h>
#include <hip/hip_bf16.h>
#include <math.h>

#define BT 32768        // B*T tokens
#define HH 1024

typedef unsigned short u16;
typedef unsigned int u32;
typedef __attribute__((ext_vector_type(4))) unsigned short u16x4;
typedef __attribute__((ext_vector_type(8))) unsigned short u16x8;
typedef __attribute__((ext_vector_type(8))) __bf16 bf16x8;
typedef __attribute__((ext_vector_type(4))) float f32x4;

#define DEVI static __device__ __forceinline__

DEVI u16 f2bf(float f){
  unsigned u = __builtin_bit_cast(unsigned, f);
  u += 0x7FFFu + ((u >> 16) & 1u);
  return (u16)(u >> 16);
}
DEVI float bf2f(u16 h){
  unsigned u = ((unsigned)h) << 16;
  return __builtin_bit_cast(float, u);
}
DEVI void gl_lds16(const void* g, void* l){
  __builtin_amdgcn_global_load_lds((const __attribute__((address_space(1))) void*)g,
                                   (__attribute__((address_space(3))) void*)l, 16, 0, 0);
}
// T2 swizzle: 16B-granule XOR within a 64-elem (128B) row. elem units of u16. Involution.
DEVI int swz(int row, int elem){ return elem ^ ((row & 7) << 3); }

// ---------------- elementwise prep kernels ----------------
__global__ void k_cast4(const float* __restrict__ s, u16* __restrict__ d, int n4){
  int i = blockIdx.x*blockDim.x + threadIdx.x;
  int st = gridDim.x*blockDim.x;
  for (; i < n4; i += st){
    float4 v = ((const float4*)s)[i];
    u16x4 o = { f2bf(v.x), f2bf(v.y), f2bf(v.z), f2bf(v.w) };
    ((u16x4*)d)[i] = o;
  }
}

// qb = bf16(query_token + static_context)
__global__ void k_qb(const float* __restrict__ qt, const float* __restrict__ sc,
                     u16* __restrict__ d, int n4){
  int i = blockIdx.x*blockDim.x + threadIdx.x;
  int st = gridDim.x*blockDim.x;
  for (; i < n4; i += st){
    int e = i*4; int c = e & 1023;
    float4 v = *(const float4*)&sc[e];
    float4 q = *(const float4*)&qt[c];
    u16x4 o = { f2bf(v.x+q.x), f2bf(v.y+q.y), f2bf(v.z+q.z), f2bf(v.w+q.w) };
    ((u16x4*)d)[i] = o;
  }
}

__global__ void k_copyf(const float* __restrict__ s, float* __restrict__ d, int n){
  int i = blockIdx.x*blockDim.x + threadIdx.x;
  int st = gridDim.x*blockDim.x;
  for (; i < n; i += st) d[i] = s[i];
}

// weights = mean over 16 heads of pbuf[t][h][m]
__global__ void k_wmean(const float* __restrict__ p, float* __restrict__ out, int n){
  int i = blockIdx.x*blockDim.x + threadIdx.x;
  int st = gridDim.x*blockDim.x;
  for (; i < n; i += st){
    int t = i/3, m = i - t*3;
    float s = 0.f;
    #pragma unroll
    for (int h = 0; h < 16; ++h) s += p[(size_t)t*48 + h*3 + m];
    out[i] = s * 0.0625f;
  }
}

// transpose-cast: s[R][C] f32 -> d[C][R] bf16
__global__ void k_transcast(const float* __restrict__ s, u16* __restrict__ d, int R, int C){
  __shared__ float tile[32][33];
  int c0 = blockIdx.x*32, r0 = blockIdx.y*32;
  int tx = threadIdx.x & 31, ty = threadIdx.x >> 5;   // 32 x 8
  #pragma unroll
  for (int i = 0; i < 32; i += 8) tile[ty+i][tx] = s[(size_t)(r0+ty+i)*C + c0+tx];
  __syncthreads();
  #pragma unroll
  for (int i = 0; i < 32; i += 8) d[(size_t)(c0+ty+i)*R + r0+tx] = f2bf(tile[tx][ty+i]);
}

// out[row] = dot(W[row,:](bf16), x(f32)) + badd[row], rows = gridDim.x*4
__global__ void k_matvec(const u16* __restrict__ W, const float* __restrict__ x,
                         const float* __restrict__ badd, float* __restrict__ out, int K){
  int row = blockIdx.x*4 + (threadIdx.x>>6);
  int lane = threadIdx.x & 63;
  float s = 0.f;
  for (int k = lane; k < K; k += 64) s += bf2f(W[(size_t)row*K + k]) * x[k];
  #pragma unroll
  for (int m = 1; m < 64; m <<= 1) s += __shfl_xor(s, m);
  if (lane == 0) out[row] = s + badd[row];
}

// ---------------- GEMM 128x128 (R2-proven) ----------------
__global__ __launch_bounds__(256, 3)
void k_gemm(const u16* __restrict__ A, int lda,
            const u16* __restrict__ B, int ldb, int K,
            const float* __restrict__ bias,
            u16* __restrict__ C, int ldc, int col0, int act)
{
  __shared__ u16 As[128*64];
  __shared__ u16 Bs[128*64];
  const int tid = threadIdx.x, lane = tid & 63, wid = tid >> 6;
  const int wr = wid >> 1, wc = wid & 1;
  const int r15 = lane & 15, g = lane >> 4;
  const int m0 = blockIdx.x * 128, n0 = blockIdx.y * 128;
  f32x4 acc[4][4] = {};

  for (int k0 = 0; k0 < K; k0 += 64){
    #pragma unroll
    for (int it = 0; it < 4; ++it){
      int c = it*256 + tid;
      int row = c >> 3;
      int ke = swz(row, (c & 7) * 8);
      gl_lds16(A + (size_t)(m0+row)*lda + (k0+ke), As + c*8);
      gl_lds16(B + (size_t)(n0+row)*ldb + (k0+ke), Bs + c*8);
    }
    __syncthreads();
    #pragma unroll
    for (int kk = 0; kk < 64; kk += 32){
      bf16x8 av[4], bvv[4];
      #pragma unroll
      for (int i = 0; i < 4; ++i){
        int row = wr*64 + i*16 + r15;
        av[i] = *(const bf16x8*)&As[row*64 + swz(row, kk + g*8)];
      }
      #pragma unroll
      for (int j = 0; j < 4; ++j){
        int row = wc*64 + j*16 + r15;
        bvv[j] = *(const bf16x8*)&Bs[row*64 + swz(row, kk + g*8)];
      }
      #pragma unroll
      for (int i = 0; i < 4; ++i)
        #pragma unroll
        for (int j = 0; j < 4; ++j)
          acc[i][j] = __builtin_amdgcn_mfma_f32_16x16x32_bf16(av[i], bvv[j], acc[i][j], 0, 0, 0);
    }
    __syncthreads();
  }
  #pragma unroll
  for (int j = 0; j < 4; ++j){
    int col = wc*64 + j*16 + r15;
    float bb = bias ? bias[n0 + col] : 0.f;
    #pragma unroll
    for (int i = 0; i < 4; ++i){
      #pragma unroll
      for (int jj = 0; jj < 4; ++jj){
        int row = wr*64 + i*16 + g*4 + jj;
        float v = acc[i][j][jj] + bb;
        if (act == 1) v = 0.5f * v * (1.f + erff(v * 0.70710678118654752f));
        C[(size_t)(m0+row)*ldc + col0 + n0 + col] = f2bf(v);
      }
    }
  }
}

// ---------------- fused attention: K-GEMM -> scores -> softmax -> V-GEMM -> ctx -------
// R15-proven form: 128 tokens x 128 cols (2 heads), 256 thr, 4 waves at 64x64.
// Q hoisted ONCE as bf16-PACKED registers (32 VGPR); launch_bounds(256,2) -- forcing 3
// blocks/CU spills (R14: 84 VGPR -> WRITE +536MB; R16 single-acc: same signature).
// This kernel is structurally 2 blocks/CU: acc pair = 128 f32. T5 setprio added around
// MFMA clusters (2 independent blocks/CU -> scheduler has something to arbitrate, m191).
__global__ __launch_bounds__(256, 2)
void k_attnf(const u16* __restrict__ x0b, const u16* __restrict__ x1b, const u16* __restrict__ x2b,
             const u16* __restrict__ Wc0, const u16* __restrict__ Wc1, const u16* __restrict__ Wc2,
             const float* __restrict__ bc0, const float* __restrict__ bc1, const float* __restrict__ bc2,
             const u16* __restrict__ Qg, u16* __restrict__ ctx, float* __restrict__ pbuf)
{
  __shared__ u16 As[128*64];
  __shared__ u16 Bs[128*64];
  __shared__ float Sl[2*128*3];    // scores -> probs (in place)
  const int tid = threadIdx.x, lane = tid & 63, wid = tid >> 6;
  const int wr = wid >> 1, wc = wid & 1;
  const int r15 = lane & 15, g = lane >> 4;
  const int bid = blockIdx.x;
  const int xcd = bid & 7, bn = (bid >> 3) & 7, btb = (bid >> 6) * 8 + xcd;
  const int t0 = btb * 128, n0 = bn * 128;

  const u16* Xs[3] = { x0b, x1b, x2b };
  const u16* Ws[3] = { Wc0, Wc1, Wc2 };
  const float* Bc[3] = { bc0, bc1, bc2 };
  const int Ks[3] = { 256, 512, 1024 };

  // hoist Q ONCE, bf16-packed: qp[i][jj][p] holds cols j=2p,2p+1 (32 VGPR total)
  u32 qp[4][4][2];
  #pragma unroll
  for (int i = 0; i < 4; ++i)
    #pragma unroll
    for (int jj = 0; jj < 4; ++jj){
      int row = wr*64 + i*16 + g*4 + jj;
      const u16* qr = Qg + (size_t)(t0+row)*1024 + n0 + wc*64 + r15;
      #pragma unroll
      for (int p = 0; p < 2; ++p)
        qp[i][jj][p] = (u32)qr[(2*p)*16] | ((u32)qr[(2*p+1)*16] << 16);
    }

  // ---------------- pass 1: K-GEMM panels + score epilogues ----------------
  #pragma unroll
  for (int m = 0; m < 3; ++m){
    const int K = Ks[m];
    const u16* X = Xs[m];
    const u16* W = Ws[m];
    f32x4 acc[4][4] = {};
    for (int k0 = 0; k0 < K; k0 += 64){
      #pragma unroll
      for (int it = 0; it < 4; ++it){
        int c = it*256 + tid;
        int row = c >> 3;
        int ke = swz(row, (c & 7) * 8);
        gl_lds16(X + (size_t)(t0+row)*K + (k0+ke), As + c*8);
        gl_lds16(W + (size_t)(n0+row)*K + (k0+ke), Bs + c*8);
      }
      __syncthreads();
      __builtin_amdgcn_s_setprio(1);
      #pragma unroll
      for (int kk = 0; kk < 64; kk += 32){
        bf16x8 av[4], bvv[4];
        #pragma unroll
        for (int i = 0; i < 4; ++i){
          int row = wr*64 + i*16 + r15;
          av[i] = *(const bf16x8*)&As[row*64 + swz(row, kk + g*8)];
        }
        #pragma unroll
        for (int j = 0; j < 4; ++j){
          int row = wc*64 + j*16 + r15;
          bvv[j] = *(const bf16x8*)&Bs[row*64 + swz(row, kk + g*8)];
        }
        #pragma unroll
        for (int i = 0; i < 4; ++i)
          #pragma unroll
          for (int j = 0; j < 4; ++j)
            acc[i][j] = __builtin_amdgcn_mfma_f32_16x16x32_bf16(av[i], bvv[j], acc[i][j], 0, 0, 0);
      }
      __builtin_amdgcn_s_setprio(0);
      __syncthreads();
    }
    // scores for modality m; this wave's head = bn*2 + wc
    float bkc[4];
    #pragma unroll
    for (int j = 0; j < 4; ++j) bkc[j] = Bc[m][n0 + wc*64 + j*16 + r15];
    #pragma unroll
    for (int i = 0; i < 4; ++i){
      #pragma unroll
      for (int jj = 0; jj < 4; ++jj){
        int row = wr*64 + i*16 + g*4 + jj;
        float sv = 0.f;
        #pragma unroll
        for (int p = 0; p < 2; ++p){
          u32 q2 = qp[i][jj][p];
          float q0 = __builtin_bit_cast(float, q2 << 16);
          float q1 = __builtin_bit_cast(float, q2 & 0xFFFF0000u);
          sv += (acc[i][2*p][jj]   + bkc[2*p])   * q0;
          sv += (acc[i][2*p+1][jj] + bkc[2*p+1]) * q1;
        }
        sv += __shfl_xor(sv, 1); sv += __shfl_xor(sv, 2);
        sv += __shfl_xor(sv, 4); sv += __shfl_xor(sv, 8);
        if (r15 == 0) Sl[(wc*128 + row)*3 + m] = sv * 0.125f;
      }
    }
  }
  __syncthreads();

  // ---------------- softmax (block-local) + per-head prob store ----------------
  {
    int h2 = tid >> 7, tt = tid & 127;
    int base = (h2*128 + tt)*3;
    float s0 = Sl[base+0], s1 = Sl[base+1], s2 = Sl[base+2];
    float mx = fmaxf(s0, fmaxf(s1, s2));
    float e0 = __expf(s0-mx), e1 = __expf(s1-mx), e2 = __expf(s2-mx);
    float inv = 1.f/(e0+e1+e2);
    e0 *= inv; e1 *= inv; e2 *= inv;
    __syncthreads();                      // all reads of raw scores done
    Sl[base+0] = e0; Sl[base+1] = e1; Sl[base+2] = e2;
    float* pp = pbuf + ((size_t)(t0+tt)*16 + (bn*2 + h2))*3;
    pp[0] = e0; pp[1] = e1; pp[2] = e2;
  }
  __syncthreads();

  // ---------------- pass 2: V-GEMM panels + p-fold ----------------
  f32x4 cx[4][4] = {};
  #pragma unroll
  for (int m = 0; m < 3; ++m){
    const int K = Ks[m];
    const u16* X = Xs[m];
    const u16* W = Ws[m] + (size_t)1024*K;   // V rows of composite weight
    f32x4 acc[4][4] = {};
    for (int k0 = 0; k0 < K; k0 += 64){
      #pragma unroll
      for (int it = 0; it < 4; ++it){
        int c = it*256 + tid;
        int row = c >> 3;
        int ke = swz(row, (c & 7) * 8);
        gl_lds16(X + (size_t)(t0+row)*K + (k0+ke), As + c*8);
        gl_lds16(W + (size_t)(n0+row)*K + (k0+ke), Bs + c*8);
      }
      __syncthreads();
      __builtin_amdgcn_s_setprio(1);
      #pragma unroll
      for (int kk = 0; kk < 64; kk += 32){
        bf16x8 av[4], bvv[4];
        #pragma unroll
        for (int i = 0; i < 4; ++i){
          int row = wr*64 + i*16 + r15;
          av[i] = *(const bf16x8*)&As[row*64 + swz(row, kk + g*8)];
        }
        #pragma unroll
        for (int j = 0; j < 4; ++j){
          int row = wc*64 + j*16 + r15;
          bvv[j] = *(const bf16x8*)&Bs[row*64 + swz(row, kk + g*8)];
        }
        #pragma unroll
        for (int i = 0; i < 4; ++i)
          #pragma unroll
          for (int j = 0; j < 4; ++j)
            acc[i][j] = __builtin_amdgcn_mfma_f32_16x16x32_bf16(av[i], bvv[j], acc[i][j], 0, 0, 0);
      }
      __builtin_amdgcn_s_setprio(0);
      __syncthreads();
    }
    // fold: cx += p(row,m) * (acc + bv_m)
    float bvc[4];
    #pragma unroll
    for (int j = 0; j < 4; ++j) bvc[j] = Bc[m][1024 + n0 + wc*64 + j*16 + r15];
    #pragma unroll
    for (int i = 0; i < 4; ++i){
      #pragma unroll
      for (int jj = 0; jj < 4; ++jj){
        int row = wr*64 + i*16 + g*4 + jj;
        float p = Sl[(wc*128 + row)*3 + m];
        #pragma unroll
        for (int j = 0; j < 4; ++j)
          cx[i][j][jj] += p * (acc[i][j][jj] + bvc[j]);
      }
    }
  }
  // write ctx
  #pragma unroll
  for (int i = 0; i < 4; ++i){
    #pragma unroll
    for (int jj = 0; jj < 4; ++jj){
      int row = wr*64 + i*16 + g*4 + jj;
      #pragma unroll
      for (int j = 0; j < 4; ++j)
        ctx[(size_t)(t0+row)*1024 + n0 + wc*64 + j*16 + r15] = f2bf(cx[i][j][jj]);
    }
  }
}

// ---------------- LayerNorm (H=1024), optional bf16 residual, bf16 or f32 out ----------------
__global__ __launch_bounds__(256)
void k_ln(const u16* __restrict__ X, const u16* __restrict__ R,
          const float* __restrict__ gam, const float* __restrict__ bet,
          u16* __restrict__ outb, float* __restrict__ outf)
{
  __shared__ float rs[4], rq[4];
  const int t = blockIdx.x, tid = threadIdx.x;
  const size_t base = (size_t)t*1024 + tid*4;
  u16x4 xv = *(const u16x4*)&X[base];
  float v[4];
  #pragma unroll
  for (int i = 0; i < 4; ++i) v[i] = bf2f(xv[i]);
  if (R){
    u16x4 rv = *(const u16x4*)&R[base];
    #pragma unroll
    for (int i = 0; i < 4; ++i) v[i] += bf2f(rv[i]);
  }
  float s = v[0]+v[1]+v[2]+v[3];
  float q = v[0]*v[0]+v[1]*v[1]+v[2]*v[2]+v[3]*v[3];
  #pragma unroll
  for (int m = 1; m < 64; m <<= 1){ s += __shfl_xor(s, m); q += __shfl_xor(q, m); }
  if ((tid & 63) == 0){ rs[tid>>6] = s; rq[tid>>6] = q; }
  __syncthreads();
  s = rs[0]+rs[1]+rs[2]+rs[3];
  q = rq[0]+rq[1]+rq[2]+rq[3];
  float mean = s * (1.f/1024.f);
  float var  = q * (1.f/1024.f) - mean*mean;
  float rstd = rsqrtf(var + 1e-5f);
  int c0 = tid*4;
  if (outb){
    u16x4 o;
    #pragma unroll
    for (int i = 0; i < 4; ++i) o[i] = f2bf((v[i]-mean)*rstd*gam[c0+i] + bet[c0+i]);
    *(u16x4*)&outb[base] = o;
  } else {
    float4 o;
    o.x = (v[0]-mean)*rstd*gam[c0+0] + bet[c0+0];
    o.y = (v[1]-mean)*rstd*gam[c0+1] + bet[c0+1];
    o.z = (v[2]-mean)*rstd*gam[c0+2] + bet[c0+2];
    o.w = (v[3]-mean)*rstd*gam[c0+3] + bet[c0+3];
    *(float4*)&outf[base] = o;
  }
}

// ---------------- host launcher ----------------
extern "C" void kernel_launch(void* const* d_in, const int* in_sizes, int n_in,
                              void* d_out, int out_size, void* d_ws, size_t ws_size,
                              hipStream_t stream)
{
  (void)in_sizes; (void)n_in; (void)out_size;
  const float* x0  = (const float*)d_in[0];
  const float* x1  = (const float*)d_in[1];
  const float* x2  = (const float*)d_in[2];
  const float* sc  = (const float*)d_in[3];
  const float* Wp0 = (const float*)d_in[4];  const float* bp0 = (const float*)d_in[5];
  const float* Wp1 = (const float*)d_in[6];  const float* bp1 = (const float*)d_in[7];
  const float* Wq  = (const float*)d_in[8];  const float* bq  = (const float*)d_in[9];
  const float* Wk  = (const float*)d_in[10]; const float* bk  = (const float*)d_in[11];
  const float* Wv  = (const float*)d_in[12]; const float* bv  = (const float*)d_in[13];
  const float* Wo  = (const float*)d_in[14]; const float* bo  = (const float*)d_in[15];
  const float* qt  = (const float*)d_in[16];
  const float* g1  = (const float*)d_in[17]; const float* be1 = (const float*)d_in[18];
  const float* g2  = (const float*)d_in[19]; const float* be2 = (const float*)d_in[20];
  const float* W1  = (const float*)d_in[21]; const float* b1  = (const float*)d_in[22];
  const float* W2  = (const float*)d_in[23]; const float* b2  = (const float*)d_in[24];

  char* ws = (char*)d_ws;
  size_t off = 0;
  auto alloc = [&](size_t b)->char*{ char* p = ws + off; off += (b + 255) & ~(size_t)255; return p; };

  u16* Wqb   = (u16*)alloc((size_t)1024*1024*2);
  u16* Wob   = (u16*)alloc((size_t)1024*1024*2);
  u16* W1b   = (u16*)alloc((size_t)4096*1024*2);
  u16* W2b   = (u16*)alloc((size_t)1024*4096*2);
  u16* Wkvb  = (u16*)alloc((size_t)2048*1024*2);  // [Wk; Wv]
  u16* Wp0t  = (u16*)alloc((size_t)256*1024*2);   // Wp0^T
  u16* Wp1t  = (u16*)alloc((size_t)512*1024*2);   // Wp1^T
  u16* Wkv0c = (u16*)alloc((size_t)2048*256*2);   // [Wk;Wv]@Wp0
  u16* Wkv1c = (u16*)alloc((size_t)2048*512*2);   // [Wk;Wv]@Wp1
  float* bc0 = (float*)alloc((size_t)2048*4);
  float* bc1 = (float*)alloc((size_t)2048*4);
  float* bc2 = (float*)alloc((size_t)2048*4);
  char* regX  = alloc((size_t)BT*(256+512+1024)*2);  // x0b|x1b|x2b -> aob -> ff2b
  char* regQ1 = alloc((size_t)BT*1024*2);            // qb -> ctxb -> f1b
  char* regQ2 = alloc((size_t)BT*1024*2);            // Qb -> ff1c (4-chunk fallback)
  float* pbuf = (float*)alloc((size_t)BT*48*4);      // per-head probs
  if (off > ws_size) return;
  // optional big FF1 buffer: 2-chunk FF path gives FF2 1024 blocks (4/CU) vs 512
  u16* ff1big = nullptr;
  if (off + (size_t)16384*4096*2 <= ws_size) ff1big = (u16*)alloc((size_t)16384*4096*2);

  u16* x0b = (u16*)regX;
  u16* x1b = (u16*)(regX + (size_t)BT*256*2);
  u16* x2b = (u16*)(regX + (size_t)BT*768*2);
  u16* aob  = (u16*)regX;
  u16* ff2b = (u16*)regX;
  u16* qb   = (u16*)regQ1;
  u16* ctxb = (u16*)regQ1;
  u16* f1b  = (u16*)regQ1;
  u16* Qb   = (u16*)regQ2;

  dim3 B256(256);
  auto cast4 = [&](const float* s, u16* d, int n, int grid){
    k_cast4<<<dim3(grid), B256, 0, stream>>>(s, d, n >> 2);
  };
  cast4(Wq, Wqb, 1024*1024, 1024);
  cast4(Wk, Wkvb, 1024*1024, 1024);
  cast4(Wv, Wkvb + (size_t)1024*1024, 1024*1024, 1024);
  cast4(Wo, Wob, 1024*1024, 1024);
  cast4(W1, W1b, 4096*1024, 1024);
  cast4(W2, W2b, 4096*1024, 1024);
  cast4(x0, x0b, BT*256, 1024);
  cast4(x1, x1b, BT*512, 1024);
  cast4(x2, x2b, BT*1024, 2048);
  k_transcast<<<dim3(8, 32),  B256, 0, stream>>>(Wp0, Wp0t, 1024, 256);
  k_transcast<<<dim3(16, 32), B256, 0, stream>>>(Wp1, Wp1t, 1024, 512);
  k_copyf<<<dim3(4), B256, 0, stream>>>(bk, bc2, 1024);
  k_copyf<<<dim3(4), B256, 0, stream>>>(bv, bc2 + 1024, 1024);
  k_matvec<<<dim3(512), B256, 0, stream>>>(Wkvb, bp0, bc2, bc0, 1024);
  k_matvec<<<dim3(512), B256, 0, stream>>>(Wkvb, bp1, bc2, bc1, 1024);
  k_qb<<<dim3(2048), B256, 0, stream>>>(qt, sc, qb, BT*256);

  // composite weights: Wkv @ Wp_m  (C[2048, IN_m])
  k_gemm<<<dim3(16, 2), B256, 0, stream>>>(Wkvb, 1024, Wp0t, 1024, 1024, nullptr, Wkv0c, 256, 0, 0);
  k_gemm<<<dim3(16, 4), B256, 0, stream>>>(Wkvb, 1024, Wp1t, 1024, 1024, nullptr, Wkv1c, 512, 0, 0);

  k_gemm<<<dim3(BT/128, 8), B256, 0, stream>>>(qb, 1024, Wqb, 1024, 1024, bq, Qb, 1024, 0, 0);
  k_attnf<<<dim3(BT/128*8), B256, 0, stream>>>(x0b, x1b, x2b, Wkv0c, Wkv1c, Wkvb,
                                               bc0, bc1, bc2, Qb, ctxb, pbuf);
  float* outf = (float*)d_out;
  k_wmean<<<dim3(384), B256, 0, stream>>>(pbuf, outf + (size_t)BT*1024, BT*3);
  k_gemm<<<dim3(BT/128, 8), B256, 0, stream>>>(ctxb, 1024, Wob, 1024, 1024, bo, aob, 1024, 0, 0);
  k_ln<<<dim3(BT), B256, 0, stream>>>(aob, nullptr, g1, be1, f1b, nullptr);

  if (ff1big){
    for (int c = 0; c < 2; ++c){
      const u16* fa = f1b + (size_t)c*16384*1024;
      k_gemm<<<dim3(128, 32), B256, 0, stream>>>(fa, 1024, W1b, 1024, 1024, b1, ff1big, 4096, 0, 1);
      k_gemm<<<dim3(128, 8),  B256, 0, stream>>>(ff1big, 4096, W2b, 4096, 4096, b2,
                                                 ff2b + (size_t)c*16384*1024, 1024, 0, 0);
    }
  } else {
    u16* ff1c = (u16*)regQ2;   // Qb dead after attn
    for (int c = 0; c < 4; ++c){
      const u16* fa = f1b + (size_t)c*8192*1024;
      k_gemm<<<dim3(64, 32), B256, 0, stream>>>(fa, 1024, W1b, 1024, 1024, b1, ff1c, 4096, 0, 1);
      k_gemm<<<dim3(64, 8),  B256, 0, stream>>>(ff1c, 4096, W2b, 4096, 4096, b2,
                                                ff2b + (size_t)c*8192*1024, 1024, 0, 0);
    }
  }
  k_ln<<<dim3(BT), B256, 0, stream>>>(ff2b, f1b, g2, be2, nullptr, outf);
}

// Round 18
// 1541.428 us; speedup vs baseline: 1.0552x; 1.0217x over previous
//
#include <hip/hip_runtime.h>
#include <hip/hip_bf16.h>
#include <math.h>

#define BT 32768        // B*T tokens
#define HH 1024

typedef unsigned short u16;
typedef unsigned int u32;
typedef __attribute__((ext_vector_type(4))) unsigned short u16x4;
typedef __attribute__((ext_vector_type(8))) unsigned short u16x8;
typedef __attribute__((ext_vector_type(8))) __bf16 bf16x8;
typedef __attribute__((ext_vector_type(4))) float f32x4;

#define DEVI static __device__ __forceinline__

DEVI u16 f2bf(float f){
  unsigned u = __builtin_bit_cast(unsigned, f);
  u += 0x7FFFu + ((u >> 16) & 1u);
  return (u16)(u >> 16);
}
DEVI float bf2f(u16 h){
  unsigned u = ((unsigned)h) << 16;
  return __builtin_bit_cast(float, u);
}
DEVI void gl_lds16(const void* g, void* l){
  __builtin_amdgcn_global_load_lds((const __attribute__((address_space(1))) void*)g,
                                   (__attribute__((address_space(3))) void*)l, 16, 0, 0);
}
// T2 swizzle: 16B-granule XOR within a 64-elem (128B) row. elem units of u16. Involution.
DEVI int swz(int row, int elem){ return elem ^ ((row & 7) << 3); }

// ---------------- elementwise prep kernels ----------------
__global__ void k_cast4(const float* __restrict__ s, u16* __restrict__ d, int n4){
  int i = blockIdx.x*blockDim.x + threadIdx.x;
  int st = gridDim.x*blockDim.x;
  for (; i < n4; i += st){
    float4 v = ((const float4*)s)[i];
    u16x4 o = { f2bf(v.x), f2bf(v.y), f2bf(v.z), f2bf(v.w) };
    ((u16x4*)d)[i] = o;
  }
}

// qb = bf16(query_token + static_context)
__global__ void k_qb(const float* __restrict__ qt, const float* __restrict__ sc,
                     u16* __restrict__ d, int n4){
  int i = blockIdx.x*blockDim.x + threadIdx.x;
  int st = gridDim.x*blockDim.x;
  for (; i < n4; i += st){
    int e = i*4; int c = e & 1023;
    float4 v = *(const float4*)&sc[e];
    float4 q = *(const float4*)&qt[c];
    u16x4 o = { f2bf(v.x+q.x), f2bf(v.y+q.y), f2bf(v.z+q.z), f2bf(v.w+q.w) };
    ((u16x4*)d)[i] = o;
  }
}

__global__ void k_copyf(const float* __restrict__ s, float* __restrict__ d, int n){
  int i = blockIdx.x*blockDim.x + threadIdx.x;
  int st = gridDim.x*blockDim.x;
  for (; i < n; i += st) d[i] = s[i];
}

// weights = mean over 16 heads of pbuf[t][h][m]
__global__ void k_wmean(const float* __restrict__ p, float* __restrict__ out, int n){
  int i = blockIdx.x*blockDim.x + threadIdx.x;
  int st = gridDim.x*blockDim.x;
  for (; i < n; i += st){
    int t = i/3, m = i - t*3;
    float s = 0.f;
    #pragma unroll
    for (int h = 0; h < 16; ++h) s += p[(size_t)t*48 + h*3 + m];
    out[i] = s * 0.0625f;
  }
}

// transpose-cast: s[R][C] f32 -> d[C][R] bf16
__global__ void k_transcast(const float* __restrict__ s, u16* __restrict__ d, int R, int C){
  __shared__ float tile[32][33];
  int c0 = blockIdx.x*32, r0 = blockIdx.y*32;
  int tx = threadIdx.x & 31, ty = threadIdx.x >> 5;   // 32 x 8
  #pragma unroll
  for (int i = 0; i < 32; i += 8) tile[ty+i][tx] = s[(size_t)(r0+ty+i)*C + c0+tx];
  __syncthreads();
  #pragma unroll
  for (int i = 0; i < 32; i += 8) d[(size_t)(c0+ty+i)*R + r0+tx] = f2bf(tile[tx][ty+i]);
}

// out[row] = dot(W[row,:](bf16), x(f32)) + badd[row], rows = gridDim.x*4
__global__ void k_matvec(const u16* __restrict__ W, const float* __restrict__ x,
                         const float* __restrict__ badd, float* __restrict__ out, int K){
  int row = blockIdx.x*4 + (threadIdx.x>>6);
  int lane = threadIdx.x & 63;
  float s = 0.f;
  for (int k = lane; k < K; k += 64) s += bf2f(W[(size_t)row*K + k]) * x[k];
  #pragma unroll
  for (int m = 1; m < 64; m <<= 1) s += __shfl_xor(s, m);
  if (lane == 0) out[row] = s + badd[row];
}

// ---------------- GEMM 128x128 (R2-proven) ----------------
__global__ __launch_bounds__(256, 3)
void k_gemm(const u16* __restrict__ A, int lda,
            const u16* __restrict__ B, int ldb, int K,
            const float* __restrict__ bias,
            u16* __restrict__ C, int ldc, int col0, int act)
{
  __shared__ u16 As[128*64];
  __shared__ u16 Bs[128*64];
  const int tid = threadIdx.x, lane = tid & 63, wid = tid >> 6;
  const int wr = wid >> 1, wc = wid & 1;
  const int r15 = lane & 15, g = lane >> 4;
  const int m0 = blockIdx.x * 128, n0 = blockIdx.y * 128;
  f32x4 acc[4][4] = {};

  for (int k0 = 0; k0 < K; k0 += 64){
    #pragma unroll
    for (int it = 0; it < 4; ++it){
      int c = it*256 + tid;
      int row = c >> 3;
      int ke = swz(row, (c & 7) * 8);
      gl_lds16(A + (size_t)(m0+row)*lda + (k0+ke), As + c*8);
      gl_lds16(B + (size_t)(n0+row)*ldb + (k0+ke), Bs + c*8);
    }
    __syncthreads();
    #pragma unroll
    for (int kk = 0; kk < 64; kk += 32){
      bf16x8 av[4], bvv[4];
      #pragma unroll
      for (int i = 0; i < 4; ++i){
        int row = wr*64 + i*16 + r15;
        av[i] = *(const bf16x8*)&As[row*64 + swz(row, kk + g*8)];
      }
      #pragma unroll
      for (int j = 0; j < 4; ++j){
        int row = wc*64 + j*16 + r15;
        bvv[j] = *(const bf16x8*)&Bs[row*64 + swz(row, kk + g*8)];
      }
      #pragma unroll
      for (int i = 0; i < 4; ++i)
        #pragma unroll
        for (int j = 0; j < 4; ++j)
          acc[i][j] = __builtin_amdgcn_mfma_f32_16x16x32_bf16(av[i], bvv[j], acc[i][j], 0, 0, 0);
    }
    __syncthreads();
  }
  #pragma unroll
  for (int j = 0; j < 4; ++j){
    int col = wc*64 + j*16 + r15;
    float bb = bias ? bias[n0 + col] : 0.f;
    #pragma unroll
    for (int i = 0; i < 4; ++i){
      #pragma unroll
      for (int jj = 0; jj < 4; ++jj){
        int row = wr*64 + i*16 + g*4 + jj;
        float v = acc[i][j][jj] + bb;
        if (act == 1) v = 0.5f * v * (1.f + erff(v * 0.70710678118654752f));
        C[(size_t)(m0+row)*ldc + col0 + n0 + col] = f2bf(v);
      }
    }
  }
}

// ---------------- fused attention: K-GEMM -> scores -> softmax -> V-GEMM -> ctx -------
// R15/R17-proven form: 128 tokens x 128 cols (2 heads), 256 thr, 4 waves at 64x64.
// Packed-Q register hoist (32 VGPR), dual accumulator, launch_bounds(256,2) (forcing 3
// blocks spills: R14/R16). T5 setprio around MFMA clusters (R17: small gain, kept).
__global__ __launch_bounds__(256, 2)
void k_attnf(const u16* __restrict__ x0b, const u16* __restrict__ x1b, const u16* __restrict__ x2b,
             const u16* __restrict__ Wc0, const u16* __restrict__ Wc1, const u16* __restrict__ Wc2,
             const float* __restrict__ bc0, const float* __restrict__ bc1, const float* __restrict__ bc2,
             const u16* __restrict__ Qg, u16* __restrict__ ctx, float* __restrict__ pbuf)
{
  __shared__ u16 As[128*64];
  __shared__ u16 Bs[128*64];
  __shared__ float Sl[2*128*3];    // scores -> probs (in place)
  const int tid = threadIdx.x, lane = tid & 63, wid = tid >> 6;
  const int wr = wid >> 1, wc = wid & 1;
  const int r15 = lane & 15, g = lane >> 4;
  const int bid = blockIdx.x;
  const int xcd = bid & 7, bn = (bid >> 3) & 7, btb = (bid >> 6) * 8 + xcd;
  const int t0 = btb * 128, n0 = bn * 128;

  const u16* Xs[3] = { x0b, x1b, x2b };
  const u16* Ws[3] = { Wc0, Wc1, Wc2 };
  const float* Bc[3] = { bc0, bc1, bc2 };
  const int Ks[3] = { 256, 512, 1024 };

  // hoist Q ONCE, bf16-packed: qp[i][jj][p] holds cols j=2p,2p+1 (32 VGPR total)
  u32 qp[4][4][2];
  #pragma unroll
  for (int i = 0; i < 4; ++i)
    #pragma unroll
    for (int jj = 0; jj < 4; ++jj){
      int row = wr*64 + i*16 + g*4 + jj;
      const u16* qr = Qg + (size_t)(t0+row)*1024 + n0 + wc*64 + r15;
      #pragma unroll
      for (int p = 0; p < 2; ++p)
        qp[i][jj][p] = (u32)qr[(2*p)*16] | ((u32)qr[(2*p+1)*16] << 16);
    }

  // ---------------- pass 1: K-GEMM panels + score epilogues ----------------
  #pragma unroll
  for (int m = 0; m < 3; ++m){
    const int K = Ks[m];
    const u16* X = Xs[m];
    const u16* W = Ws[m];
    f32x4 acc[4][4] = {};
    for (int k0 = 0; k0 < K; k0 += 64){
      #pragma unroll
      for (int it = 0; it < 4; ++it){
        int c = it*256 + tid;
        int row = c >> 3;
        int ke = swz(row, (c & 7) * 8);
        gl_lds16(X + (size_t)(t0+row)*K + (k0+ke), As + c*8);
        gl_lds16(W + (size_t)(n0+row)*K + (k0+ke), Bs + c*8);
      }
      __syncthreads();
      __builtin_amdgcn_s_setprio(1);
      #pragma unroll
      for (int kk = 0; kk < 64; kk += 32){
        bf16x8 av[4], bvv[4];
        #pragma unroll
        for (int i = 0; i < 4; ++i){
          int row = wr*64 + i*16 + r15;
          av[i] = *(const bf16x8*)&As[row*64 + swz(row, kk + g*8)];
        }
        #pragma unroll
        for (int j = 0; j < 4; ++j){
          int row = wc*64 + j*16 + r15;
          bvv[j] = *(const bf16x8*)&Bs[row*64 + swz(row, kk + g*8)];
        }
        #pragma unroll
        for (int i = 0; i < 4; ++i)
          #pragma unroll
          for (int j = 0; j < 4; ++j)
            acc[i][j] = __builtin_amdgcn_mfma_f32_16x16x32_bf16(av[i], bvv[j], acc[i][j], 0, 0, 0);
      }
      __builtin_amdgcn_s_setprio(0);
      __syncthreads();
    }
    // scores for modality m; this wave's head = bn*2 + wc
    float bkc[4];
    #pragma unroll
    for (int j = 0; j < 4; ++j) bkc[j] = Bc[m][n0 + wc*64 + j*16 + r15];
    #pragma unroll
    for (int i = 0; i < 4; ++i){
      #pragma unroll
      for (int jj = 0; jj < 4; ++jj){
        int row = wr*64 + i*16 + g*4 + jj;
        float sv = 0.f;
        #pragma unroll
        for (int p = 0; p < 2; ++p){
          u32 q2 = qp[i][jj][p];
          float q0 = __builtin_bit_cast(float, q2 << 16);
          float q1 = __builtin_bit_cast(float, q2 & 0xFFFF0000u);
          sv += (acc[i][2*p][jj]   + bkc[2*p])   * q0;
          sv += (acc[i][2*p+1][jj] + bkc[2*p+1]) * q1;
        }
        sv += __shfl_xor(sv, 1); sv += __shfl_xor(sv, 2);
        sv += __shfl_xor(sv, 4); sv += __shfl_xor(sv, 8);
        if (r15 == 0) Sl[(wc*128 + row)*3 + m] = sv * 0.125f;
      }
    }
  }
  __syncthreads();

  // ---------------- softmax (block-local) + per-head prob store ----------------
  {
    int h2 = tid >> 7, tt = tid & 127;
    int base = (h2*128 + tt)*3;
    float s0 = Sl[base+0], s1 = Sl[base+1], s2 = Sl[base+2];
    float mx = fmaxf(s0, fmaxf(s1, s2));
    float e0 = __expf(s0-mx), e1 = __expf(s1-mx), e2 = __expf(s2-mx);
    float inv = 1.f/(e0+e1+e2);
    e0 *= inv; e1 *= inv; e2 *= inv;
    __syncthreads();                      // all reads of raw scores done
    Sl[base+0] = e0; Sl[base+1] = e1; Sl[base+2] = e2;
    float* pp = pbuf + ((size_t)(t0+tt)*16 + (bn*2 + h2))*3;
    pp[0] = e0; pp[1] = e1; pp[2] = e2;
  }
  __syncthreads();

  // ---------------- pass 2: V-GEMM panels + p-fold ----------------
  f32x4 cx[4][4] = {};
  #pragma unroll
  for (int m = 0; m < 3; ++m){
    const int K = Ks[m];
    const u16* X = Xs[m];
    const u16* W = Ws[m] + (size_t)1024*K;   // V rows of composite weight
    f32x4 acc[4][4] = {};
    for (int k0 = 0; k0 < K; k0 += 64){
      #pragma unroll
      for (int it = 0; it < 4; ++it){
        int c = it*256 + tid;
        int row = c >> 3;
        int ke = swz(row, (c & 7) * 8);
        gl_lds16(X + (size_t)(t0+row)*K + (k0+ke), As + c*8);
        gl_lds16(W + (size_t)(n0+row)*K + (k0+ke), Bs + c*8);
      }
      __syncthreads();
      __builtin_amdgcn_s_setprio(1);
      #pragma unroll
      for (int kk = 0; kk < 64; kk += 32){
        bf16x8 av[4], bvv[4];
        #pragma unroll
        for (int i = 0; i < 4; ++i){
          int row = wr*64 + i*16 + r15;
          av[i] = *(const bf16x8*)&As[row*64 + swz(row, kk + g*8)];
        }
        #pragma unroll
        for (int j = 0; j < 4; ++j){
          int row = wc*64 + j*16 + r15;
          bvv[j] = *(const bf16x8*)&Bs[row*64 + swz(row, kk + g*8)];
        }
        #pragma unroll
        for (int i = 0; i < 4; ++i)
          #pragma unroll
          for (int j = 0; j < 4; ++j)
            acc[i][j] = __builtin_amdgcn_mfma_f32_16x16x32_bf16(av[i], bvv[j], acc[i][j], 0, 0, 0);
      }
      __builtin_amdgcn_s_setprio(0);
      __syncthreads();
    }
    // fold: cx += p(row,m) * (acc + bv_m)
    float bvc[4];
    #pragma unroll
    for (int j = 0; j < 4; ++j) bvc[j] = Bc[m][1024 + n0 + wc*64 + j*16 + r15];
    #pragma unroll
    for (int i = 0; i < 4; ++i){
      #pragma unroll
      for (int jj = 0; jj < 4; ++jj){
        int row = wr*64 + i*16 + g*4 + jj;
        float p = Sl[(wc*128 + row)*3 + m];
        #pragma unroll
        for (int j = 0; j < 4; ++j)
          cx[i][j][jj] += p * (acc[i][j][jj] + bvc[j]);
      }
    }
  }
  // write ctx
  #pragma unroll
  for (int i = 0; i < 4; ++i){
    #pragma unroll
    for (int jj = 0; jj < 4; ++jj){
      int row = wr*64 + i*16 + g*4 + jj;
      #pragma unroll
      for (int j = 0; j < 4; ++j)
        ctx[(size_t)(t0+row)*1024 + n0 + wc*64 + j*16 + r15] = f2bf(cx[i][j][jj]);
    }
  }
}

// ---------------- LayerNorm (H=1024), optional bf16 residual, bf16 or f32 out ----------------
__global__ __launch_bounds__(256)
void k_ln(const u16* __restrict__ X, const u16* __restrict__ R,
          const float* __restrict__ gam, const float* __restrict__ bet,
          u16* __restrict__ outb, float* __restrict__ outf)
{
  __shared__ float rs[4], rq[4];
  const int t = blockIdx.x, tid = threadIdx.x;
  const size_t base = (size_t)t*1024 + tid*4;
  u16x4 xv = *(const u16x4*)&X[base];
  float v[4];
  #pragma unroll
  for (int i = 0; i < 4; ++i) v[i] = bf2f(xv[i]);
  if (R){
    u16x4 rv = *(const u16x4*)&R[base];
    #pragma unroll
    for (int i = 0; i < 4; ++i) v[i] += bf2f(rv[i]);
  }
  float s = v[0]+v[1]+v[2]+v[3];
  float q = v[0]*v[0]+v[1]*v[1]+v[2]*v[2]+v[3]*v[3];
  #pragma unroll
  for (int m = 1; m < 64; m <<= 1){ s += __shfl_xor(s, m); q += __shfl_xor(q, m); }
  if ((tid & 63) == 0){ rs[tid>>6] = s; rq[tid>>6] = q; }
  __syncthreads();
  s = rs[0]+rs[1]+rs[2]+rs[3];
  q = rq[0]+rq[1]+rq[2]+rq[3];
  float mean = s * (1.f/1024.f);
  float var  = q * (1.f/1024.f) - mean*mean;
  float rstd = rsqrtf(var + 1e-5f);
  int c0 = tid*4;
  if (outb){
    u16x4 o;
    #pragma unroll
    for (int i = 0; i < 4; ++i) o[i] = f2bf((v[i]-mean)*rstd*gam[c0+i] + bet[c0+i]);
    *(u16x4*)&outb[base] = o;
  } else {
    float4 o;
    o.x = (v[0]-mean)*rstd*gam[c0+0] + bet[c0+0];
    o.y = (v[1]-mean)*rstd*gam[c0+1] + bet[c0+1];
    o.z = (v[2]-mean)*rstd*gam[c0+2] + bet[c0+2];
    o.w = (v[3]-mean)*rstd*gam[c0+3] + bet[c0+3];
    *(float4*)&outf[base] = o;
  }
}

// ---------------- host launcher ----------------
extern "C" void kernel_launch(void* const* d_in, const int* in_sizes, int n_in,
                              void* d_out, int out_size, void* d_ws, size_t ws_size,
                              hipStream_t stream)
{
  (void)in_sizes; (void)n_in; (void)out_size;
  const float* x0  = (const float*)d_in[0];
  const float* x1  = (const float*)d_in[1];
  const float* x2  = (const float*)d_in[2];
  const float* sc  = (const float*)d_in[3];
  const float* Wp0 = (const float*)d_in[4];  const float* bp0 = (const float*)d_in[5];
  const float* Wp1 = (const float*)d_in[6];  const float* bp1 = (const float*)d_in[7];
  const float* Wq  = (const float*)d_in[8];  const float* bq  = (const float*)d_in[9];
  const float* Wk  = (const float*)d_in[10]; const float* bk  = (const float*)d_in[11];
  const float* Wv  = (const float*)d_in[12]; const float* bv  = (const float*)d_in[13];
  const float* Wo  = (const float*)d_in[14]; const float* bo  = (const float*)d_in[15];
  const float* qt  = (const float*)d_in[16];
  const float* g1  = (const float*)d_in[17]; const float* be1 = (const float*)d_in[18];
  const float* g2  = (const float*)d_in[19]; const float* be2 = (const float*)d_in[20];
  const float* W1  = (const float*)d_in[21]; const float* b1  = (const float*)d_in[22];
  const float* W2  = (const float*)d_in[23]; const float* b2  = (const float*)d_in[24];

  char* ws = (char*)d_ws;
  size_t off = 0;
  auto alloc = [&](size_t b)->char*{ char* p = ws + off; off += (b + 255) & ~(size_t)255; return p; };

  u16* Wqb   = (u16*)alloc((size_t)1024*1024*2);
  u16* Wob   = (u16*)alloc((size_t)1024*1024*2);
  u16* W1b   = (u16*)alloc((size_t)4096*1024*2);
  u16* W2b   = (u16*)alloc((size_t)1024*4096*2);
  u16* Wkvb  = (u16*)alloc((size_t)2048*1024*2);  // [Wk; Wv]
  u16* Wp0t  = (u16*)alloc((size_t)256*1024*2);   // Wp0^T
  u16* Wp1t  = (u16*)alloc((size_t)512*1024*2);   // Wp1^T
  u16* Wkv0c = (u16*)alloc((size_t)2048*256*2);   // [Wk;Wv]@Wp0
  u16* Wkv1c = (u16*)alloc((size_t)2048*512*2);   // [Wk;Wv]@Wp1
  float* bc0 = (float*)alloc((size_t)2048*4);
  float* bc1 = (float*)alloc((size_t)2048*4);
  float* bc2 = (float*)alloc((size_t)2048*4);
  char* regX  = alloc((size_t)BT*(256+512+1024)*2);  // x0b|x1b|x2b -> aob -> ff2b
  char* regQ1 = alloc((size_t)BT*1024*2);            // qb -> ctxb -> f1b
  char* regQ2 = alloc((size_t)BT*1024*2);            // Qb -> ff1c
  float* pbuf = (float*)alloc((size_t)BT*48*4);      // per-head probs
  if (off > ws_size) return;

  u16* x0b = (u16*)regX;
  u16* x1b = (u16*)(regX + (size_t)BT*256*2);
  u16* x2b = (u16*)(regX + (size_t)BT*768*2);
  u16* aob  = (u16*)regX;
  u16* ff2b = (u16*)regX;
  u16* qb   = (u16*)regQ1;
  u16* ctxb = (u16*)regQ1;
  u16* f1b  = (u16*)regQ1;
  u16* Qb   = (u16*)regQ2;
  u16* ff1c = (u16*)regQ2;

  dim3 B256(256);
  auto cast4 = [&](const float* s, u16* d, int n, int grid){
    k_cast4<<<dim3(grid), B256, 0, stream>>>(s, d, n >> 2);
  };
  cast4(Wq, Wqb, 1024*1024, 1024);
  cast4(Wk, Wkvb, 1024*1024, 1024);
  cast4(Wv, Wkvb + (size_t)1024*1024, 1024*1024, 1024);
  cast4(Wo, Wob, 1024*1024, 1024);
  cast4(W1, W1b, 4096*1024, 1024);
  cast4(W2, W2b, 4096*1024, 1024);
  cast4(x0, x0b, BT*256, 1024);
  cast4(x1, x1b, BT*512, 1024);
  cast4(x2, x2b, BT*1024, 2048);
  k_transcast<<<dim3(8, 32),  B256, 0, stream>>>(Wp0, Wp0t, 1024, 256);
  k_transcast<<<dim3(16, 32), B256, 0, stream>>>(Wp1, Wp1t, 1024, 512);
  k_copyf<<<dim3(4), B256, 0, stream>>>(bk, bc2, 1024);
  k_copyf<<<dim3(4), B256, 0, stream>>>(bv, bc2 + 1024, 1024);
  k_matvec<<<dim3(512), B256, 0, stream>>>(Wkvb, bp0, bc2, bc0, 1024);
  k_matvec<<<dim3(512), B256, 0, stream>>>(Wkvb, bp1, bc2, bc1, 1024);
  k_qb<<<dim3(2048), B256, 0, stream>>>(qt, sc, qb, BT*256);

  // composite weights: Wkv @ Wp_m  (C[2048, IN_m])
  k_gemm<<<dim3(16, 2), B256, 0, stream>>>(Wkvb, 1024, Wp0t, 1024, 1024, nullptr, Wkv0c, 256, 0, 0);
  k_gemm<<<dim3(16, 4), B256, 0, stream>>>(Wkvb, 1024, Wp1t, 1024, 1024, nullptr, Wkv1c, 512, 0, 0);

  k_gemm<<<dim3(BT/128, 8), B256, 0, stream>>>(qb, 1024, Wqb, 1024, 1024, bq, Qb, 1024, 0, 0);
  k_attnf<<<dim3(BT/128*8), B256, 0, stream>>>(x0b, x1b, x2b, Wkv0c, Wkv1c, Wkvb,
                                               bc0, bc1, bc2, Qb, ctxb, pbuf);
  float* outf = (float*)d_out;
  k_wmean<<<dim3(384), B256, 0, stream>>>(pbuf, outf + (size_t)BT*1024, BT*3);
  k_gemm<<<dim3(BT/128, 8), B256, 0, stream>>>(ctxb, 1024, Wob, 1024, 1024, bo, aob, 1024, 0, 0);
  k_ln<<<dim3(BT), B256, 0, stream>>>(aob, nullptr, g1, be1, f1b, nullptr);

  for (int c = 0; c < 4; ++c){
    const u16* fa = f1b + (size_t)c*8192*1024;
    k_gemm<<<dim3(64, 32), B256, 0, stream>>>(fa, 1024, W1b, 1024, 1024, b1, ff1c, 4096, 0, 1);
    k_gemm<<<dim3(64, 8),  B256, 0, stream>>>(ff1c, 4096, W2b, 4096, 4096, b2,
                                              ff2b + (size_t)c*8192*1024, 1024, 0, 0);
  }
  k_ln<<<dim3(BT), B256, 0, stream>>>(ff2b, f1b, g2, be2, nullptr, outf);
}

// Round 19
// 1522.501 us; speedup vs baseline: 1.0684x; 1.0124x over previous
//
#include <hip/hip_runtime.h>
#include <hip/hip_bf16.h>
#include <math.h>

#define BT 32768        // B*T tokens
#define HH 1024

typedef unsigned short u16;
typedef unsigned int u32;
typedef __attribute__((ext_vector_type(4))) unsigned short u16x4;
typedef __attribute__((ext_vector_type(8))) unsigned short u16x8;
typedef __attribute__((ext_vector_type(8))) __bf16 bf16x8;
typedef __attribute__((ext_vector_type(4))) float f32x4;

#define DEVI static __device__ __forceinline__

DEVI u16 f2bf(float f){
  unsigned u = __builtin_bit_cast(unsigned, f);
  u += 0x7FFFu + ((u >> 16) & 1u);
  return (u16)(u >> 16);
}
DEVI float bf2f(u16 h){
  unsigned u = ((unsigned)h) << 16;
  return __builtin_bit_cast(float, u);
}
DEVI void gl_lds16(const void* g, void* l){
  __builtin_amdgcn_global_load_lds((const __attribute__((address_space(1))) void*)g,
                                   (__attribute__((address_space(3))) void*)l, 16, 0, 0);
}
// T2 swizzle: 16B-granule XOR within a 64-elem (128B) row. elem units of u16. Involution.
DEVI int swz(int row, int elem){ return elem ^ ((row & 7) << 3); }

// ---------------- fused prep: 10 f32->bf16 cast segments in ONE launch ----------------
// seg 9 is qb = bf16(sc + qt[c]) (qt broadcast over the 1024-col dim).
struct PrepSegs {
  const float* src[10];
  u16* dst[10];
  long long cum[11];     // cumulative n4 (float4-chunk) offsets
  const float* qt;       // broadcast source for segment 9
};

__global__ void k_prepall(PrepSegs S, long long total_n4){
  long long i = (long long)blockIdx.x*blockDim.x + threadIdx.x;
  long long st = (long long)gridDim.x*blockDim.x;
  for (; i < total_n4; i += st){
    int s = 0;
    #pragma unroll
    for (int k = 1; k < 10; ++k) s += (i >= S.cum[k]) ? 1 : 0;
    long long local = i - S.cum[s];
    float4 v = ((const float4*)S.src[s])[local];
    if (s == 9){
      int c = (int)((local*4) & 1023);
      v.x += S.qt[c]; v.y += S.qt[c+1]; v.z += S.qt[c+2]; v.w += S.qt[c+3];
    }
    u16x4 o = { f2bf(v.x), f2bf(v.y), f2bf(v.z), f2bf(v.w) };
    ((u16x4*)S.dst[s])[local] = o;
  }
}

__global__ void k_copyf(const float* __restrict__ s, float* __restrict__ d, int n){
  int i = blockIdx.x*blockDim.x + threadIdx.x;
  int st = gridDim.x*blockDim.x;
  for (; i < n; i += st) d[i] = s[i];
}

// weights = mean over 16 heads of pbuf[t][h][m]
__global__ void k_wmean(const float* __restrict__ p, float* __restrict__ out, int n){
  int i = blockIdx.x*blockDim.x + threadIdx.x;
  int st = gridDim.x*blockDim.x;
  for (; i < n; i += st){
    int t = i/3, m = i - t*3;
    float s = 0.f;
    #pragma unroll
    for (int h = 0; h < 16; ++h) s += p[(size_t)t*48 + h*3 + m];
    out[i] = s * 0.0625f;
  }
}

// transpose-cast: s[R][C] f32 -> d[C][R] bf16
__global__ void k_transcast(const float* __restrict__ s, u16* __restrict__ d, int R, int C){
  __shared__ float tile[32][33];
  int c0 = blockIdx.x*32, r0 = blockIdx.y*32;
  int tx = threadIdx.x & 31, ty = threadIdx.x >> 5;   // 32 x 8
  #pragma unroll
  for (int i = 0; i < 32; i += 8) tile[ty+i][tx] = s[(size_t)(r0+ty+i)*C + c0+tx];
  __syncthreads();
  #pragma unroll
  for (int i = 0; i < 32; i += 8) d[(size_t)(c0+ty+i)*R + r0+tx] = f2bf(tile[tx][ty+i]);
}

// out[row] = dot(W[row,:](bf16), x(f32)) + badd[row], rows = gridDim.x*4
__global__ void k_matvec(const u16* __restrict__ W, const float* __restrict__ x,
                         const float* __restrict__ badd, float* __restrict__ out, int K){
  int row = blockIdx.x*4 + (threadIdx.x>>6);
  int lane = threadIdx.x & 63;
  float s = 0.f;
  for (int k = lane; k < K; k += 64) s += bf2f(W[(size_t)row*K + k]) * x[k];
  #pragma unroll
  for (int m = 1; m < 64; m <<= 1) s += __shfl_xor(s, m);
  if (lane == 0) out[row] = s + badd[row];
}

// ---------------- GEMM 128x128 (R2-proven) ----------------
__global__ __launch_bounds__(256, 3)
void k_gemm(const u16* __restrict__ A, int lda,
            const u16* __restrict__ B, int ldb, int K,
            const float* __restrict__ bias,
            u16* __restrict__ C, int ldc, int col0, int act)
{
  __shared__ u16 As[128*64];
  __shared__ u16 Bs[128*64];
  const int tid = threadIdx.x, lane = tid & 63, wid = tid >> 6;
  const int wr = wid >> 1, wc = wid & 1;
  const int r15 = lane & 15, g = lane >> 4;
  const int m0 = blockIdx.x * 128, n0 = blockIdx.y * 128;
  f32x4 acc[4][4] = {};

  for (int k0 = 0; k0 < K; k0 += 64){
    #pragma unroll
    for (int it = 0; it < 4; ++it){
      int c = it*256 + tid;
      int row = c >> 3;
      int ke = swz(row, (c & 7) * 8);
      gl_lds16(A + (size_t)(m0+row)*lda + (k0+ke), As + c*8);
      gl_lds16(B + (size_t)(n0+row)*ldb + (k0+ke), Bs + c*8);
    }
    __syncthreads();
    #pragma unroll
    for (int kk = 0; kk < 64; kk += 32){
      bf16x8 av[4], bvv[4];
      #pragma unroll
      for (int i = 0; i < 4; ++i){
        int row = wr*64 + i*16 + r15;
        av[i] = *(const bf16x8*)&As[row*64 + swz(row, kk + g*8)];
      }
      #pragma unroll
      for (int j = 0; j < 4; ++j){
        int row = wc*64 + j*16 + r15;
        bvv[j] = *(const bf16x8*)&Bs[row*64 + swz(row, kk + g*8)];
      }
      #pragma unroll
      for (int i = 0; i < 4; ++i)
        #pragma unroll
        for (int j = 0; j < 4; ++j)
          acc[i][j] = __builtin_amdgcn_mfma_f32_16x16x32_bf16(av[i], bvv[j], acc[i][j], 0, 0, 0);
    }
    __syncthreads();
  }
  #pragma unroll
  for (int j = 0; j < 4; ++j){
    int col = wc*64 + j*16 + r15;
    float bb = bias ? bias[n0 + col] : 0.f;
    #pragma unroll
    for (int i = 0; i < 4; ++i){
      #pragma unroll
      for (int jj = 0; jj < 4; ++jj){
        int row = wr*64 + i*16 + g*4 + jj;
        float v = acc[i][j][jj] + bb;
        if (act == 1) v = 0.5f * v * (1.f + erff(v * 0.70710678118654752f));
        C[(size_t)(m0+row)*ldc + col0 + n0 + col] = f2bf(v);
      }
    }
  }
}

// ---------------- fused attention: K-GEMM -> scores -> softmax -> V-GEMM -> ctx -------
// R15/R17-proven form: 128 tokens x 128 cols (2 heads), 256 thr, 4 waves at 64x64.
// Packed-Q register hoist (32 VGPR), dual accumulator, launch_bounds(256,2) (forcing 3
// blocks spills: R14/R16). T5 setprio around MFMA clusters (R17: small gain, kept).
__global__ __launch_bounds__(256, 2)
void k_attnf(const u16* __restrict__ x0b, const u16* __restrict__ x1b, const u16* __restrict__ x2b,
             const u16* __restrict__ Wc0, const u16* __restrict__ Wc1, const u16* __restrict__ Wc2,
             const float* __restrict__ bc0, const float* __restrict__ bc1, const float* __restrict__ bc2,
             const u16* __restrict__ Qg, u16* __restrict__ ctx, float* __restrict__ pbuf)
{
  __shared__ u16 As[128*64];
  __shared__ u16 Bs[128*64];
  __shared__ float Sl[2*128*3];    // scores -> probs (in place)
  const int tid = threadIdx.x, lane = tid & 63, wid = tid >> 6;
  const int wr = wid >> 1, wc = wid & 1;
  const int r15 = lane & 15, g = lane >> 4;
  const int bid = blockIdx.x;
  const int xcd = bid & 7, bn = (bid >> 3) & 7, btb = (bid >> 6) * 8 + xcd;
  const int t0 = btb * 128, n0 = bn * 128;

  const u16* Xs[3] = { x0b, x1b, x2b };
  const u16* Ws[3] = { Wc0, Wc1, Wc2 };
  const float* Bc[3] = { bc0, bc1, bc2 };
  const int Ks[3] = { 256, 512, 1024 };

  // hoist Q ONCE, bf16-packed: qp[i][jj][p] holds cols j=2p,2p+1 (32 VGPR total)
  u32 qp[4][4][2];
  #pragma unroll
  for (int i = 0; i < 4; ++i)
    #pragma unroll
    for (int jj = 0; jj < 4; ++jj){
      int row = wr*64 + i*16 + g*4 + jj;
      const u16* qr = Qg + (size_t)(t0+row)*1024 + n0 + wc*64 + r15;
      #pragma unroll
      for (int p = 0; p < 2; ++p)
        qp[i][jj][p] = (u32)qr[(2*p)*16] | ((u32)qr[(2*p+1)*16] << 16);
    }

  // ---------------- pass 1: K-GEMM panels + score epilogues ----------------
  #pragma unroll
  for (int m = 0; m < 3; ++m){
    const int K = Ks[m];
    const u16* X = Xs[m];
    const u16* W = Ws[m];
    f32x4 acc[4][4] = {};
    for (int k0 = 0; k0 < K; k0 += 64){
      #pragma unroll
      for (int it = 0; it < 4; ++it){
        int c = it*256 + tid;
        int row = c >> 3;
        int ke = swz(row, (c & 7) * 8);
        gl_lds16(X + (size_t)(t0+row)*K + (k0+ke), As + c*8);
        gl_lds16(W + (size_t)(n0+row)*K + (k0+ke), Bs + c*8);
      }
      __syncthreads();
      __builtin_amdgcn_s_setprio(1);
      #pragma unroll
      for (int kk = 0; kk < 64; kk += 32){
        bf16x8 av[4], bvv[4];
        #pragma unroll
        for (int i = 0; i < 4; ++i){
          int row = wr*64 + i*16 + r15;
          av[i] = *(const bf16x8*)&As[row*64 + swz(row, kk + g*8)];
        }
        #pragma unroll
        for (int j = 0; j < 4; ++j){
          int row = wc*64 + j*16 + r15;
          bvv[j] = *(const bf16x8*)&Bs[row*64 + swz(row, kk + g*8)];
        }
        #pragma unroll
        for (int i = 0; i < 4; ++i)
          #pragma unroll
          for (int j = 0; j < 4; ++j)
            acc[i][j] = __builtin_amdgcn_mfma_f32_16x16x32_bf16(av[i], bvv[j], acc[i][j], 0, 0, 0);
      }
      __builtin_amdgcn_s_setprio(0);
      __syncthreads();
    }
    // scores for modality m; this wave's head = bn*2 + wc
    float bkc[4];
    #pragma unroll
    for (int j = 0; j < 4; ++j) bkc[j] = Bc[m][n0 + wc*64 + j*16 + r15];
    #pragma unroll
    for (int i = 0; i < 4; ++i){
      #pragma unroll
      for (int jj = 0; jj < 4; ++jj){
        int row = wr*64 + i*16 + g*4 + jj;
        float sv = 0.f;
        #pragma unroll
        for (int p = 0; p < 2; ++p){
          u32 q2 = qp[i][jj][p];
          float q0 = __builtin_bit_cast(float, q2 << 16);
          float q1 = __builtin_bit_cast(float, q2 & 0xFFFF0000u);
          sv += (acc[i][2*p][jj]   + bkc[2*p])   * q0;
          sv += (acc[i][2*p+1][jj] + bkc[2*p+1]) * q1;
        }
        sv += __shfl_xor(sv, 1); sv += __shfl_xor(sv, 2);
        sv += __shfl_xor(sv, 4); sv += __shfl_xor(sv, 8);
        if (r15 == 0) Sl[(wc*128 + row)*3 + m] = sv * 0.125f;
      }
    }
  }
  __syncthreads();

  // ---------------- softmax (block-local) + per-head prob store ----------------
  {
    int h2 = tid >> 7, tt = tid & 127;
    int base = (h2*128 + tt)*3;
    float s0 = Sl[base+0], s1 = Sl[base+1], s2 = Sl[base+2];
    float mx = fmaxf(s0, fmaxf(s1, s2));
    float e0 = __expf(s0-mx), e1 = __expf(s1-mx), e2 = __expf(s2-mx);
    float inv = 1.f/(e0+e1+e2);
    e0 *= inv; e1 *= inv; e2 *= inv;
    __syncthreads();                      // all reads of raw scores done
    Sl[base+0] = e0; Sl[base+1] = e1; Sl[base+2] = e2;
    float* pp = pbuf + ((size_t)(t0+tt)*16 + (bn*2 + h2))*3;
    pp[0] = e0; pp[1] = e1; pp[2] = e2;
  }
  __syncthreads();

  // ---------------- pass 2: V-GEMM panels + p-fold ----------------
  f32x4 cx[4][4] = {};
  #pragma unroll
  for (int m = 0; m < 3; ++m){
    const int K = Ks[m];
    const u16* X = Xs[m];
    const u16* W = Ws[m] + (size_t)1024*K;   // V rows of composite weight
    f32x4 acc[4][4] = {};
    for (int k0 = 0; k0 < K; k0 += 64){
      #pragma unroll
      for (int it = 0; it < 4; ++it){
        int c = it*256 + tid;
        int row = c >> 3;
        int ke = swz(row, (c & 7) * 8);
        gl_lds16(X + (size_t)(t0+row)*K + (k0+ke), As + c*8);
        gl_lds16(W + (size_t)(n0+row)*K + (k0+ke), Bs + c*8);
      }
      __syncthreads();
      __builtin_amdgcn_s_setprio(1);
      #pragma unroll
      for (int kk = 0; kk < 64; kk += 32){
        bf16x8 av[4], bvv[4];
        #pragma unroll
        for (int i = 0; i < 4; ++i){
          int row = wr*64 + i*16 + r15;
          av[i] = *(const bf16x8*)&As[row*64 + swz(row, kk + g*8)];
        }
        #pragma unroll
        for (int j = 0; j < 4; ++j){
          int row = wc*64 + j*16 + r15;
          bvv[j] = *(const bf16x8*)&Bs[row*64 + swz(row, kk + g*8)];
        }
        #pragma unroll
        for (int i = 0; i < 4; ++i)
          #pragma unroll
          for (int j = 0; j < 4; ++j)
            acc[i][j] = __builtin_amdgcn_mfma_f32_16x16x32_bf16(av[i], bvv[j], acc[i][j], 0, 0, 0);
      }
      __builtin_amdgcn_s_setprio(0);
      __syncthreads();
    }
    // fold: cx += p(row,m) * (acc + bv_m)
    float bvc[4];
    #pragma unroll
    for (int j = 0; j < 4; ++j) bvc[j] = Bc[m][1024 + n0 + wc*64 + j*16 + r15];
    #pragma unroll
    for (int i = 0; i < 4; ++i){
      #pragma unroll
      for (int jj = 0; jj < 4; ++jj){
        int row = wr*64 + i*16 + g*4 + jj;
        float p = Sl[(wc*128 + row)*3 + m];
        #pragma unroll
        for (int j = 0; j < 4; ++j)
          cx[i][j][jj] += p * (acc[i][j][jj] + bvc[j]);
      }
    }
  }
  // write ctx
  #pragma unroll
  for (int i = 0; i < 4; ++i){
    #pragma unroll
    for (int jj = 0; jj < 4; ++jj){
      int row = wr*64 + i*16 + g*4 + jj;
      #pragma unroll
      for (int j = 0; j < 4; ++j)
        ctx[(size_t)(t0+row)*1024 + n0 + wc*64 + j*16 + r15] = f2bf(cx[i][j][jj]);
    }
  }
}

// ---------------- LayerNorm (H=1024), optional bf16 residual, bf16 or f32 out ----------------
__global__ __launch_bounds__(256)
void k_ln(const u16* __restrict__ X, const u16* __restrict__ R,
          const float* __restrict__ gam, const float* __restrict__ bet,
          u16* __restrict__ outb, float* __restrict__ outf)
{
  __shared__ float rs[4], rq[4];
  const int t = blockIdx.x, tid = threadIdx.x;
  const size_t base = (size_t)t*1024 + tid*4;
  u16x4 xv = *(const u16x4*)&X[base];
  float v[4];
  #pragma unroll
  for (int i = 0; i < 4; ++i) v[i] = bf2f(xv[i]);
  if (R){
    u16x4 rv = *(const u16x4*)&R[base];
    #pragma unroll
    for (int i = 0; i < 4; ++i) v[i] += bf2f(rv[i]);
  }
  float s = v[0]+v[1]+v[2]+v[3];
  float q = v[0]*v[0]+v[1]*v[1]+v[2]*v[2]+v[3]*v[3];
  #pragma unroll
  for (int m = 1; m < 64; m <<= 1){ s += __shfl_xor(s, m); q += __shfl_xor(q, m); }
  if ((tid & 63) == 0){ rs[tid>>6] = s; rq[tid>>6] = q; }
  __syncthreads();
  s = rs[0]+rs[1]+rs[2]+rs[3];
  q = rq[0]+rq[1]+rq[2]+rq[3];
  float mean = s * (1.f/1024.f);
  float var  = q * (1.f/1024.f) - mean*mean;
  float rstd = rsqrtf(var + 1e-5f);
  int c0 = tid*4;
  if (outb){
    u16x4 o;
    #pragma unroll
    for (int i = 0; i < 4; ++i) o[i] = f2bf((v[i]-mean)*rstd*gam[c0+i] + bet[c0+i]);
    *(u16x4*)&outb[base] = o;
  } else {
    float4 o;
    o.x = (v[0]-mean)*rstd*gam[c0+0] + bet[c0+0];
    o.y = (v[1]-mean)*rstd*gam[c0+1] + bet[c0+1];
    o.z = (v[2]-mean)*rstd*gam[c0+2] + bet[c0+2];
    o.w = (v[3]-mean)*rstd*gam[c0+3] + bet[c0+3];
    *(float4*)&outf[base] = o;
  }
}

// ---------------- host launcher ----------------
extern "C" void kernel_launch(void* const* d_in, const int* in_sizes, int n_in,
                              void* d_out, int out_size, void* d_ws, size_t ws_size,
                              hipStream_t stream)
{
  (void)in_sizes; (void)n_in; (void)out_size;
  const float* x0  = (const float*)d_in[0];
  const float* x1  = (const float*)d_in[1];
  const float* x2  = (const float*)d_in[2];
  const float* sc  = (const float*)d_in[3];
  const float* Wp0 = (const float*)d_in[4];  const float* bp0 = (const float*)d_in[5];
  const float* Wp1 = (const float*)d_in[6];  const float* bp1 = (const float*)d_in[7];
  const float* Wq  = (const float*)d_in[8];  const float* bq  = (const float*)d_in[9];
  const float* Wk  = (const float*)d_in[10]; const float* bk  = (const float*)d_in[11];
  const float* Wv  = (const float*)d_in[12]; const float* bv  = (const float*)d_in[13];
  const float* Wo  = (const float*)d_in[14]; const float* bo  = (const float*)d_in[15];
  const float* qt  = (const float*)d_in[16];
  const float* g1  = (const float*)d_in[17]; const float* be1 = (const float*)d_in[18];
  const float* g2  = (const float*)d_in[19]; const float* be2 = (const float*)d_in[20];
  const float* W1  = (const float*)d_in[21]; const float* b1  = (const float*)d_in[22];
  const float* W2  = (const float*)d_in[23]; const float* b2  = (const float*)d_in[24];

  char* ws = (char*)d_ws;
  size_t off = 0;
  auto alloc = [&](size_t b)->char*{ char* p = ws + off; off += (b + 255) & ~(size_t)255; return p; };

  u16* Wqb   = (u16*)alloc((size_t)1024*1024*2);
  u16* Wob   = (u16*)alloc((size_t)1024*1024*2);
  u16* W1b   = (u16*)alloc((size_t)4096*1024*2);
  u16* W2b   = (u16*)alloc((size_t)1024*4096*2);
  u16* Wkvb  = (u16*)alloc((size_t)2048*1024*2);  // [Wk; Wv]
  u16* Wp0t  = (u16*)alloc((size_t)256*1024*2);   // Wp0^T
  u16* Wp1t  = (u16*)alloc((size_t)512*1024*2);   // Wp1^T
  u16* Wkv0c = (u16*)alloc((size_t)2048*256*2);   // [Wk;Wv]@Wp0
  u16* Wkv1c = (u16*)alloc((size_t)2048*512*2);   // [Wk;Wv]@Wp1
  float* bc0 = (float*)alloc((size_t)2048*4);
  float* bc1 = (float*)alloc((size_t)2048*4);
  float* bc2 = (float*)alloc((size_t)2048*4);
  char* regX  = alloc((size_t)BT*(256+512+1024)*2);  // x0b|x1b|x2b -> aob -> ff2b
  char* regQ1 = alloc((size_t)BT*1024*2);            // qb -> ctxb -> f1b
  char* regQ2 = alloc((size_t)BT*1024*2);            // Qb -> ff1c
  float* pbuf = (float*)alloc((size_t)BT*48*4);      // per-head probs
  if (off > ws_size) return;

  u16* x0b = (u16*)regX;
  u16* x1b = (u16*)(regX + (size_t)BT*256*2);
  u16* x2b = (u16*)(regX + (size_t)BT*768*2);
  u16* aob  = (u16*)regX;
  u16* ff2b = (u16*)regX;
  u16* qb   = (u16*)regQ1;
  u16* ctxb = (u16*)regQ1;
  u16* f1b  = (u16*)regQ1;
  u16* Qb   = (u16*)regQ2;
  u16* ff1c = (u16*)regQ2;

  dim3 B256(256);

  // ---- fused prep: all f32->bf16 casts + qb in ONE launch ----
  {
    PrepSegs S;
    long long n4s[10];
    auto seg = [&](int idx, const float* s, u16* d, long long nelem){
      S.src[idx] = s; S.dst[idx] = d; n4s[idx] = nelem >> 2;
    };
    seg(0, Wq, Wqb, 1024*1024);
    seg(1, Wk, Wkvb, 1024*1024);
    seg(2, Wv, Wkvb + (size_t)1024*1024, 1024*1024);
    seg(3, Wo, Wob, 1024*1024);
    seg(4, W1, W1b, (long long)4096*1024);
    seg(5, W2, W2b, (long long)4096*1024);
    seg(6, x0, x0b, (long long)BT*256);
    seg(7, x1, x1b, (long long)BT*512);
    seg(8, x2, x2b, (long long)BT*1024);
    seg(9, sc, qb,  (long long)BT*1024);   // qb = bf16(sc + qt[c])
    S.cum[0] = 0;
    for (int k = 0; k < 10; ++k) S.cum[k+1] = S.cum[k] + n4s[k];
    S.qt = qt;
    k_prepall<<<dim3(2048), B256, 0, stream>>>(S, S.cum[10]);
  }

  k_transcast<<<dim3(8, 32),  B256, 0, stream>>>(Wp0, Wp0t, 1024, 256);
  k_transcast<<<dim3(16, 32), B256, 0, stream>>>(Wp1, Wp1t, 1024, 512);
  k_copyf<<<dim3(4), B256, 0, stream>>>(bk, bc2, 1024);
  k_copyf<<<dim3(4), B256, 0, stream>>>(bv, bc2 + 1024, 1024);
  k_matvec<<<dim3(512), B256, 0, stream>>>(Wkvb, bp0, bc2, bc0, 1024);
  k_matvec<<<dim3(512), B256, 0, stream>>>(Wkvb, bp1, bc2, bc1, 1024);

  // composite weights: Wkv @ Wp_m  (C[2048, IN_m])
  k_gemm<<<dim3(16, 2), B256, 0, stream>>>(Wkvb, 1024, Wp0t, 1024, 1024, nullptr, Wkv0c, 256, 0, 0);
  k_gemm<<<dim3(16, 4), B256, 0, stream>>>(Wkvb, 1024, Wp1t, 1024, 1024, nullptr, Wkv1c, 512, 0, 0);

  k_gemm<<<dim3(BT/128, 8), B256, 0, stream>>>(qb, 1024, Wqb, 1024, 1024, bq, Qb, 1024, 0, 0);
  k_attnf<<<dim3(BT/128*8), B256, 0, stream>>>(x0b, x1b, x2b, Wkv0c, Wkv1c, Wkvb,
                                               bc0, bc1, bc2, Qb, ctxb, pbuf);
  float* outf = (float*)d_out;
  k_wmean<<<dim3(384), B256, 0, stream>>>(pbuf, outf + (size_t)BT*1024, BT*3);
  k_gemm<<<dim3(BT/128, 8), B256, 0, stream>>>(ctxb, 1024, Wob, 1024, 1024, bo, aob, 1024, 0, 0);
  k_ln<<<dim3(BT), B256, 0, stream>>>(aob, nullptr, g1, be1, f1b, nullptr);

  for (int c = 0; c < 4; ++c){
    const u16* fa = f1b + (size_t)c*8192*1024;
    k_gemm<<<dim3(64, 32), B256, 0, stream>>>(fa, 1024, W1b, 1024, 1024, b1, ff1c, 4096, 0, 1);
    k_gemm<<<dim3(64, 8),  B256, 0, stream>>>(ff1c, 4096, W2b, 4096, 4096, b2,
                                              ff2b + (size_t)c*8192*1024, 1024, 0, 0);
  }
  k_ln<<<dim3(BT), B256, 0, stream>>>(ff2b, f1b, g2, be2, nullptr, outf);
}

// Round 20
// 1494.211 us; speedup vs baseline: 1.0886x; 1.0189x over previous
//
#include <hip/hip_runtime.h>
#include <hip/hip_bf16.h>
#include <math.h>

#define BT 32768        // B*T tokens
#define HH 1024

typedef unsigned short u16;
typedef unsigned int u32;
typedef __attribute__((ext_vector_type(4))) unsigned short u16x4;
typedef __attribute__((ext_vector_type(8))) unsigned short u16x8;
typedef __attribute__((ext_vector_type(8))) __bf16 bf16x8;
typedef __attribute__((ext_vector_type(4))) float f32x4;

#define DEVI static __device__ __forceinline__

DEVI u16 f2bf(float f){
  unsigned u = __builtin_bit_cast(unsigned, f);
  u += 0x7FFFu + ((u >> 16) & 1u);
  return (u16)(u >> 16);
}
DEVI float bf2f(u16 h){
  unsigned u = ((unsigned)h) << 16;
  return __builtin_bit_cast(float, u);
}
DEVI void gl_lds16(const void* g, void* l){
  __builtin_amdgcn_global_load_lds((const __attribute__((address_space(1))) void*)g,
                                   (__attribute__((address_space(3))) void*)l, 16, 0, 0);
}
// T2 swizzle: 16B-granule XOR within a 64-elem (128B) row. elem units of u16. Involution.
DEVI int swz(int row, int elem){ return elem ^ ((row & 7) << 3); }

// tanh-form gelu (max |err| vs erf-form ~3e-4; ~3x cheaper than erff)
DEVI float gelu_t(float v){
  float z = 0.7978845608028654f*(v + 0.044715f*v*v*v);
  float t = 1.f - 2.f/(__expf(2.f*z) + 1.f);
  return 0.5f*v*(1.f + t);
}

// ---------------- fused prep: 10 f32->bf16 cast segments in ONE launch ----------------
// seg 9 is qb = bf16(sc + qt[c]) (qt broadcast over the 1024-col dim).
struct PrepSegs {
  const float* src[10];
  u16* dst[10];
  long long cum[11];     // cumulative n4 (float4-chunk) offsets
  const float* qt;       // broadcast source for segment 9
};

__global__ void k_prepall(PrepSegs S, long long total_n4){
  long long i = (long long)blockIdx.x*blockDim.x + threadIdx.x;
  long long st = (long long)gridDim.x*blockDim.x;
  for (; i < total_n4; i += st){
    int s = 0;
    #pragma unroll
    for (int k = 1; k < 10; ++k) s += (i >= S.cum[k]) ? 1 : 0;
    long long local = i - S.cum[s];
    float4 v = ((const float4*)S.src[s])[local];
    if (s == 9){
      int c = (int)((local*4) & 1023);
      v.x += S.qt[c]; v.y += S.qt[c+1]; v.z += S.qt[c+2]; v.w += S.qt[c+3];
    }
    u16x4 o = { f2bf(v.x), f2bf(v.y), f2bf(v.z), f2bf(v.w) };
    ((u16x4*)S.dst[s])[local] = o;
  }
}

// weights = mean over 16 heads of pbuf[t][h][m]
__global__ void k_wmean(const float* __restrict__ p, float* __restrict__ out, int n){
  int i = blockIdx.x*blockDim.x + threadIdx.x;
  int st = gridDim.x*blockDim.x;
  for (; i < n; i += st){
    int t = i/3, m = i - t*3;
    float s = 0.f;
    #pragma unroll
    for (int h = 0; h < 16; ++h) s += p[(size_t)t*48 + h*3 + m];
    out[i] = s * 0.0625f;
  }
}

// transpose-cast: s[R][C] f32 -> d[C][R] bf16
__global__ void k_transcast(const float* __restrict__ s, u16* __restrict__ d, int R, int C){
  __shared__ float tile[32][33];
  int c0 = blockIdx.x*32, r0 = blockIdx.y*32;
  int tx = threadIdx.x & 31, ty = threadIdx.x >> 5;   // 32 x 8
  #pragma unroll
  for (int i = 0; i < 32; i += 8) tile[ty+i][tx] = s[(size_t)(r0+ty+i)*C + c0+tx];
  __syncthreads();
  #pragma unroll
  for (int i = 0; i < 32; i += 8) d[(size_t)(c0+ty+i)*R + r0+tx] = f2bf(tile[tx][ty+i]);
}

// fused bias prep: bc0 = Wkv@bp0 + [bk;bv], bc1 = Wkv@bp1 + [bk;bv], bc2 = [bk;bv]
// grid = 1024 blocks of 256 (4 rows each); blocks 0-511 -> bc0 (+bc2 write), 512-1023 -> bc1
__global__ void k_biasprep(const u16* __restrict__ W, const float* __restrict__ bp0,
                           const float* __restrict__ bp1, const float* __restrict__ bk,
                           const float* __restrict__ bv, float* __restrict__ bc0,
                           float* __restrict__ bc1, float* __restrict__ bc2){
  int half = blockIdx.x >> 9;
  int row = (blockIdx.x & 511)*4 + (threadIdx.x>>6);
  int lane = threadIdx.x & 63;
  const float* x = half ? bp1 : bp0;
  float s = 0.f;
  for (int k = lane; k < 1024; k += 64) s += bf2f(W[(size_t)row*1024 + k]) * x[k];
  #pragma unroll
  for (int m = 1; m < 64; m <<= 1) s += __shfl_xor(s, m);
  if (lane == 0){
    float badd = row < 1024 ? bk[row] : bv[row-1024];
    (half ? bc1 : bc0)[row] = s + badd;
    if (!half) bc2[row] = badd;
  }
}

// ---------------- GEMM 128x128 (R2-proven) ----------------
__global__ __launch_bounds__(256, 3)
void k_gemm(const u16* __restrict__ A, int lda,
            const u16* __restrict__ B, int ldb, int K,
            const float* __restrict__ bias,
            u16* __restrict__ C, int ldc, int col0, int act)
{
  __shared__ u16 As[128*64];
  __shared__ u16 Bs[128*64];
  const int tid = threadIdx.x, lane = tid & 63, wid = tid >> 6;
  const int wr = wid >> 1, wc = wid & 1;
  const int r15 = lane & 15, g = lane >> 4;
  const int m0 = blockIdx.x * 128, n0 = blockIdx.y * 128;
  f32x4 acc[4][4] = {};

  for (int k0 = 0; k0 < K; k0 += 64){
    #pragma unroll
    for (int it = 0; it < 4; ++it){
      int c = it*256 + tid;
      int row = c >> 3;
      int ke = swz(row, (c & 7) * 8);
      gl_lds16(A + (size_t)(m0+row)*lda + (k0+ke), As + c*8);
      gl_lds16(B + (size_t)(n0+row)*ldb + (k0+ke), Bs + c*8);
    }
    __syncthreads();
    #pragma unroll
    for (int kk = 0; kk < 64; kk += 32){
      bf16x8 av[4], bvv[4];
      #pragma unroll
      for (int i = 0; i < 4; ++i){
        int row = wr*64 + i*16 + r15;
        av[i] = *(const bf16x8*)&As[row*64 + swz(row, kk + g*8)];
      }
      #pragma unroll
      for (int j = 0; j < 4; ++j){
        int row = wc*64 + j*16 + r15;
        bvv[j] = *(const bf16x8*)&Bs[row*64 + swz(row, kk + g*8)];
      }
      #pragma unroll
      for (int i = 0; i < 4; ++i)
        #pragma unroll
        for (int j = 0; j < 4; ++j)
          acc[i][j] = __builtin_amdgcn_mfma_f32_16x16x32_bf16(av[i], bvv[j], acc[i][j], 0, 0, 0);
    }
    __syncthreads();
  }
  #pragma unroll
  for (int j = 0; j < 4; ++j){
    int col = wc*64 + j*16 + r15;
    float bb = bias ? bias[n0 + col] : 0.f;
    #pragma unroll
    for (int i = 0; i < 4; ++i){
      #pragma unroll
      for (int jj = 0; jj < 4; ++jj){
        int row = wr*64 + i*16 + g*4 + jj;
        float v = acc[i][j][jj] + bb;
        if (act == 1) v = gelu_t(v);
        C[(size_t)(m0+row)*ldc + col0 + n0 + col] = f2bf(v);
      }
    }
  }
}

// ---------------- fused attention: K-GEMM -> scores -> softmax -> V-GEMM -> ctx -------
// R15/R17-proven form: 128 tokens x 128 cols (2 heads), 256 thr, 4 waves at 64x64.
// Packed-Q register hoist (32 VGPR), dual accumulator, launch_bounds(256,2) (forcing 3
// blocks spills: R14/R16). T5 setprio around MFMA clusters (R17: small gain, kept).
__global__ __launch_bounds__(256, 2)
void k_attnf(const u16* __restrict__ x0b, const u16* __restrict__ x1b, const u16* __restrict__ x2b,
             const u16* __restrict__ Wc0, const u16* __restrict__ Wc1, const u16* __restrict__ Wc2,
             const float* __restrict__ bc0, const float* __restrict__ bc1, const float* __restrict__ bc2,
             const u16* __restrict__ Qg, u16* __restrict__ ctx, float* __restrict__ pbuf)
{
  __shared__ u16 As[128*64];
  __shared__ u16 Bs[128*64];
  __shared__ float Sl[2*128*3];    // scores -> probs (in place)
  const int tid = threadIdx.x, lane = tid & 63, wid = tid >> 6;
  const int wr = wid >> 1, wc = wid & 1;
  const int r15 = lane & 15, g = lane >> 4;
  const int bid = blockIdx.x;
  const int xcd = bid & 7, bn = (bid >> 3) & 7, btb = (bid >> 6) * 8 + xcd;
  const int t0 = btb * 128, n0 = bn * 128;

  const u16* Xs[3] = { x0b, x1b, x2b };
  const u16* Ws[3] = { Wc0, Wc1, Wc2 };
  const float* Bc[3] = { bc0, bc1, bc2 };
  const int Ks[3] = { 256, 512, 1024 };

  // hoist Q ONCE, bf16-packed: qp[i][jj][p] holds cols j=2p,2p+1 (32 VGPR total)
  u32 qp[4][4][2];
  #pragma unroll
  for (int i = 0; i < 4; ++i)
    #pragma unroll
    for (int jj = 0; jj < 4; ++jj){
      int row = wr*64 + i*16 + g*4 + jj;
      const u16* qr = Qg + (size_t)(t0+row)*1024 + n0 + wc*64 + r15;
      #pragma unroll
      for (int p = 0; p < 2; ++p)
        qp[i][jj][p] = (u32)qr[(2*p)*16] | ((u32)qr[(2*p+1)*16] << 16);
    }

  // ---------------- pass 1: K-GEMM panels + score epilogues ----------------
  #pragma unroll
  for (int m = 0; m < 3; ++m){
    const int K = Ks[m];
    const u16* X = Xs[m];
    const u16* W = Ws[m];
    f32x4 acc[4][4] = {};
    for (int k0 = 0; k0 < K; k0 += 64){
      #pragma unroll
      for (int it = 0; it < 4; ++it){
        int c = it*256 + tid;
        int row = c >> 3;
        int ke = swz(row, (c & 7) * 8);
        gl_lds16(X + (size_t)(t0+row)*K + (k0+ke), As + c*8);
        gl_lds16(W + (size_t)(n0+row)*K + (k0+ke), Bs + c*8);
      }
      __syncthreads();
      __builtin_amdgcn_s_setprio(1);
      #pragma unroll
      for (int kk = 0; kk < 64; kk += 32){
        bf16x8 av[4], bvv[4];
        #pragma unroll
        for (int i = 0; i < 4; ++i){
          int row = wr*64 + i*16 + r15;
          av[i] = *(const bf16x8*)&As[row*64 + swz(row, kk + g*8)];
        }
        #pragma unroll
        for (int j = 0; j < 4; ++j){
          int row = wc*64 + j*16 + r15;
          bvv[j] = *(const bf16x8*)&Bs[row*64 + swz(row, kk + g*8)];
        }
        #pragma unroll
        for (int i = 0; i < 4; ++i)
          #pragma unroll
          for (int j = 0; j < 4; ++j)
            acc[i][j] = __builtin_amdgcn_mfma_f32_16x16x32_bf16(av[i], bvv[j], acc[i][j], 0, 0, 0);
      }
      __builtin_amdgcn_s_setprio(0);
      __syncthreads();
    }
    // scores for modality m; this wave's head = bn*2 + wc
    float bkc[4];
    #pragma unroll
    for (int j = 0; j < 4; ++j) bkc[j] = Bc[m][n0 + wc*64 + j*16 + r15];
    #pragma unroll
    for (int i = 0; i < 4; ++i){
      #pragma unroll
      for (int jj = 0; jj < 4; ++jj){
        int row = wr*64 + i*16 + g*4 + jj;
        float sv = 0.f;
        #pragma unroll
        for (int p = 0; p < 2; ++p){
          u32 q2 = qp[i][jj][p];
          float q0 = __builtin_bit_cast(float, q2 << 16);
          float q1 = __builtin_bit_cast(float, q2 & 0xFFFF0000u);
          sv += (acc[i][2*p][jj]   + bkc[2*p])   * q0;
          sv += (acc[i][2*p+1][jj] + bkc[2*p+1]) * q1;
        }
        sv += __shfl_xor(sv, 1); sv += __shfl_xor(sv, 2);
        sv += __shfl_xor(sv, 4); sv += __shfl_xor(sv, 8);
        if (r15 == 0) Sl[(wc*128 + row)*3 + m] = sv * 0.125f;
      }
    }
  }
  __syncthreads();

  // ---------------- softmax (block-local) + per-head prob store ----------------
  {
    int h2 = tid >> 7, tt = tid & 127;
    int base = (h2*128 + tt)*3;
    float s0 = Sl[base+0], s1 = Sl[base+1], s2 = Sl[base+2];
    float mx = fmaxf(s0, fmaxf(s1, s2));
    float e0 = __expf(s0-mx), e1 = __expf(s1-mx), e2 = __expf(s2-mx);
    float inv = 1.f/(e0+e1+e2);
    e0 *= inv; e1 *= inv; e2 *= inv;
    __syncthreads();                      // all reads of raw scores done
    Sl[base+0] = e0; Sl[base+1] = e1; Sl[base+2] = e2;
    float* pp = pbuf + ((size_t)(t0+tt)*16 + (bn*2 + h2))*3;
    pp[0] = e0; pp[1] = e1; pp[2] = e2;
  }
  __syncthreads();

  // ---------------- pass 2: V-GEMM panels + p-fold ----------------
  f32x4 cx[4][4] = {};
  #pragma unroll
  for (int m = 0; m < 3; ++m){
    const int K = Ks[m];
    const u16* X = Xs[m];
    const u16* W = Ws[m] + (size_t)1024*K;   // V rows of composite weight
    f32x4 acc[4][4] = {};
    for (int k0 = 0; k0 < K; k0 += 64){
      #pragma unroll
      for (int it = 0; it < 4; ++it){
        int c = it*256 + tid;
        int row = c >> 3;
        int ke = swz(row, (c & 7) * 8);
        gl_lds16(X + (size_t)(t0+row)*K + (k0+ke), As + c*8);
        gl_lds16(W + (size_t)(n0+row)*K + (k0+ke), Bs + c*8);
      }
      __syncthreads();
      __builtin_amdgcn_s_setprio(1);
      #pragma unroll
      for (int kk = 0; kk < 64; kk += 32){
        bf16x8 av[4], bvv[4];
        #pragma unroll
        for (int i = 0; i < 4; ++i){
          int row = wr*64 + i*16 + r15;
          av[i] = *(const bf16x8*)&As[row*64 + swz(row, kk + g*8)];
        }
        #pragma unroll
        for (int j = 0; j < 4; ++j){
          int row = wc*64 + j*16 + r15;
          bvv[j] = *(const bf16x8*)&Bs[row*64 + swz(row, kk + g*8)];
        }
        #pragma unroll
        for (int i = 0; i < 4; ++i)
          #pragma unroll
          for (int j = 0; j < 4; ++j)
            acc[i][j] = __builtin_amdgcn_mfma_f32_16x16x32_bf16(av[i], bvv[j], acc[i][j], 0, 0, 0);
      }
      __builtin_amdgcn_s_setprio(0);
      __syncthreads();
    }
    // fold: cx += p(row,m) * (acc + bv_m)
    float bvc[4];
    #pragma unroll
    for (int j = 0; j < 4; ++j) bvc[j] = Bc[m][1024 + n0 + wc*64 + j*16 + r15];
    #pragma unroll
    for (int i = 0; i < 4; ++i){
      #pragma unroll
      for (int jj = 0; jj < 4; ++jj){
        int row = wr*64 + i*16 + g*4 + jj;
        float p = Sl[(wc*128 + row)*3 + m];
        #pragma unroll
        for (int j = 0; j < 4; ++j)
          cx[i][j][jj] += p * (acc[i][j][jj] + bvc[j]);
      }
    }
  }
  // write ctx
  #pragma unroll
  for (int i = 0; i < 4; ++i){
    #pragma unroll
    for (int jj = 0; jj < 4; ++jj){
      int row = wr*64 + i*16 + g*4 + jj;
      #pragma unroll
      for (int j = 0; j < 4; ++j)
        ctx[(size_t)(t0+row)*1024 + n0 + wc*64 + j*16 + r15] = f2bf(cx[i][j][jj]);
    }
  }
}

// ---------------- LayerNorm (H=1024), optional bf16 residual, bf16 or f32 out ----------------
__global__ __launch_bounds__(256)
void k_ln(const u16* __restrict__ X, const u16* __restrict__ R,
          const float* __restrict__ gam, const float* __restrict__ bet,
          u16* __restrict__ outb, float* __restrict__ outf)
{
  __shared__ float rs[4], rq[4];
  const int t = blockIdx.x, tid = threadIdx.x;
  const size_t base = (size_t)t*1024 + tid*4;
  u16x4 xv = *(const u16x4*)&X[base];
  float v[4];
  #pragma unroll
  for (int i = 0; i < 4; ++i) v[i] = bf2f(xv[i]);
  if (R){
    u16x4 rv = *(const u16x4*)&R[base];
    #pragma unroll
    for (int i = 0; i < 4; ++i) v[i] += bf2f(rv[i]);
  }
  float s = v[0]+v[1]+v[2]+v[3];
  float q = v[0]*v[0]+v[1]*v[1]+v[2]*v[2]+v[3]*v[3];
  #pragma unroll
  for (int m = 1; m < 64; m <<= 1){ s += __shfl_xor(s, m); q += __shfl_xor(q, m); }
  if ((tid & 63) == 0){ rs[tid>>6] = s; rq[tid>>6] = q; }
  __syncthreads();
  s = rs[0]+rs[1]+rs[2]+rs[3];
  q = rq[0]+rq[1]+rq[2]+rq[3];
  float mean = s * (1.f/1024.f);
  float var  = q * (1.f/1024.f) - mean*mean;
  float rstd = rsqrtf(var + 1e-5f);
  int c0 = tid*4;
  if (outb){
    u16x4 o;
    #pragma unroll
    for (int i = 0; i < 4; ++i) o[i] = f2bf((v[i]-mean)*rstd*gam[c0+i] + bet[c0+i]);
    *(u16x4*)&outb[base] = o;
  } else {
    float4 o;
    o.x = (v[0]-mean)*rstd*gam[c0+0] + bet[c0+0];
    o.y = (v[1]-mean)*rstd*gam[c0+1] + bet[c0+1];
    o.z = (v[2]-mean)*rstd*gam[c0+2] + bet[c0+2];
    o.w = (v[3]-mean)*rstd*gam[c0+3] + bet[c0+3];
    *(float4*)&outf[base] = o;
  }
}

// ---------------- host launcher ----------------
extern "C" void kernel_launch(void* const* d_in, const int* in_sizes, int n_in,
                              void* d_out, int out_size, void* d_ws, size_t ws_size,
                              hipStream_t stream)
{
  (void)in_sizes; (void)n_in; (void)out_size;
  const float* x0  = (const float*)d_in[0];
  const float* x1  = (const float*)d_in[1];
  const float* x2  = (const float*)d_in[2];
  const float* sc  = (const float*)d_in[3];
  const float* Wp0 = (const float*)d_in[4];  const float* bp0 = (const float*)d_in[5];
  const float* Wp1 = (const float*)d_in[6];  const float* bp1 = (const float*)d_in[7];
  const float* Wq  = (const float*)d_in[8];  const float* bq  = (const float*)d_in[9];
  const float* Wk  = (const float*)d_in[10]; const float* bk  = (const float*)d_in[11];
  const float* Wv  = (const float*)d_in[12]; const float* bv  = (const float*)d_in[13];
  const float* Wo  = (const float*)d_in[14]; const float* bo  = (const float*)d_in[15];
  const float* qt  = (const float*)d_in[16];
  const float* g1  = (const float*)d_in[17]; const float* be1 = (const float*)d_in[18];
  const float* g2  = (const float*)d_in[19]; const float* be2 = (const float*)d_in[20];
  const float* W1  = (const float*)d_in[21]; const float* b1  = (const float*)d_in[22];
  const float* W2  = (const float*)d_in[23]; const float* b2  = (const float*)d_in[24];

  char* ws = (char*)d_ws;
  size_t off = 0;
  auto alloc = [&](size_t b)->char*{ char* p = ws + off; off += (b + 255) & ~(size_t)255; return p; };

  u16* Wqb   = (u16*)alloc((size_t)1024*1024*2);
  u16* Wob   = (u16*)alloc((size_t)1024*1024*2);
  u16* W1b   = (u16*)alloc((size_t)4096*1024*2);
  u16* W2b   = (u16*)alloc((size_t)1024*4096*2);
  u16* Wkvb  = (u16*)alloc((size_t)2048*1024*2);  // [Wk; Wv]
  u16* Wp0t  = (u16*)alloc((size_t)256*1024*2);   // Wp0^T
  u16* Wp1t  = (u16*)alloc((size_t)512*1024*2);   // Wp1^T
  u16* Wkv0c = (u16*)alloc((size_t)2048*256*2);   // [Wk;Wv]@Wp0
  u16* Wkv1c = (u16*)alloc((size_t)2048*512*2);   // [Wk;Wv]@Wp1
  float* bc0 = (float*)alloc((size_t)2048*4);
  float* bc1 = (float*)alloc((size_t)2048*4);
  float* bc2 = (float*)alloc((size_t)2048*4);
  char* regX  = alloc((size_t)BT*(256+512+1024)*2);  // x0b|x1b|x2b -> aob -> ff2b
  char* regQ1 = alloc((size_t)BT*1024*2);            // qb -> ctxb -> f1b
  char* regQ2 = alloc((size_t)BT*1024*2);            // Qb -> ff1c
  float* pbuf = (float*)alloc((size_t)BT*48*4);      // per-head probs
  if (off > ws_size) return;

  u16* x0b = (u16*)regX;
  u16* x1b = (u16*)(regX + (size_t)BT*256*2);
  u16* x2b = (u16*)(regX + (size_t)BT*768*2);
  u16* aob  = (u16*)regX;
  u16* ff2b = (u16*)regX;
  u16* qb   = (u16*)regQ1;
  u16* ctxb = (u16*)regQ1;
  u16* f1b  = (u16*)regQ1;
  u16* Qb   = (u16*)regQ2;
  u16* ff1c = (u16*)regQ2;

  dim3 B256(256);

  // ---- fused prep: all f32->bf16 casts + qb in ONE launch ----
  {
    PrepSegs S;
    long long n4s[10];
    auto seg = [&](int idx, const float* s, u16* d, long long nelem){
      S.src[idx] = s; S.dst[idx] = d; n4s[idx] = nelem >> 2;
    };
    seg(0, Wq, Wqb, 1024*1024);
    seg(1, Wk, Wkvb, 1024*1024);
    seg(2, Wv, Wkvb + (size_t)1024*1024, 1024*1024);
    seg(3, Wo, Wob, 1024*1024);
    seg(4, W1, W1b, (long long)4096*1024);
    seg(5, W2, W2b, (long long)4096*1024);
    seg(6, x0, x0b, (long long)BT*256);
    seg(7, x1, x1b, (long long)BT*512);
    seg(8, x2, x2b, (long long)BT*1024);
    seg(9, sc, qb,  (long long)BT*1024);   // qb = bf16(sc + qt[c])
    S.cum[0] = 0;
    for (int k = 0; k < 10; ++k) S.cum[k+1] = S.cum[k] + n4s[k];
    S.qt = qt;
    k_prepall<<<dim3(2048), B256, 0, stream>>>(S, S.cum[10]);
  }

  k_transcast<<<dim3(8, 32),  B256, 0, stream>>>(Wp0, Wp0t, 1024, 256);
  k_transcast<<<dim3(16, 32), B256, 0, stream>>>(Wp1, Wp1t, 1024, 512);
  k_biasprep<<<dim3(1024), B256, 0, stream>>>(Wkvb, bp0, bp1, bk, bv, bc0, bc1, bc2);

  // composite weights: Wkv @ Wp_m  (C[2048, IN_m])
  k_gemm<<<dim3(16, 2), B256, 0, stream>>>(Wkvb, 1024, Wp0t, 1024, 1024, nullptr, Wkv0c, 256, 0, 0);
  k_gemm<<<dim3(16, 4), B256, 0, stream>>>(Wkvb, 1024, Wp1t, 1024, 1024, nullptr, Wkv1c, 512, 0, 0);

  k_gemm<<<dim3(BT/128, 8), B256, 0, stream>>>(qb, 1024, Wqb, 1024, 1024, bq, Qb, 1024, 0, 0);
  k_attnf<<<dim3(BT/128*8), B256, 0, stream>>>(x0b, x1b, x2b, Wkv0c, Wkv1c, Wkvb,
                                               bc0, bc1, bc2, Qb, ctxb, pbuf);
  float* outf = (float*)d_out;
  k_wmean<<<dim3(384), B256, 0, stream>>>(pbuf, outf + (size_t)BT*1024, BT*3);
  k_gemm<<<dim3(BT/128, 8), B256, 0, stream>>>(ctxb, 1024, Wob, 1024, 1024, bo, aob, 1024, 0, 0);
  k_ln<<<dim3(BT), B256, 0, stream>>>(aob, nullptr, g1, be1, f1b, nullptr);

  for (int c = 0; c < 4; ++c){
    const u16* fa = f1b + (size_t)c*8192*1024;
    k_gemm<<<dim3(64, 32), B256, 0, stream>>>(fa, 1024, W1b, 1024, 1024, b1, ff1c, 4096, 0, 1);
    k_gemm<<<dim3(64, 8),  B256, 0, stream>>>(ff1c, 4096, W2b, 4096, 4096, b2,
                                              ff2b + (size_t)c*8192*1024, 1024, 0, 0);
  }
  k_ln<<<dim3(BT), B256, 0, stream>>>(ff2b, f1b, g2, be2, nullptr, outf);
}